// Round 2
// baseline (411.092 us; speedup 1.0000x reference)
//
#include <hip/hip_runtime.h>
#include <cstdint>
#include <cstddef>

typedef unsigned short u16;
typedef __attribute__((ext_vector_type(8))) short s16x8;
typedef __attribute__((ext_vector_type(4))) float f32x4;

#define DEV __device__ __forceinline__

DEV float bf2f(short u){
  union { unsigned int i; float f; } v;
  v.i = ((unsigned int)(u16)u) << 16;
  return v.f;
}
DEV short f2bf(float f){
  union { float f; unsigned int i; } v; v.f = f;
  unsigned int u = v.i;
  u += 0x7fffu + ((u >> 16) & 1u);   // RNE
  return (short)(u >> 16);
}
DEV s16x8 s16x8_zero(){
  s16x8 z;
#pragma unroll
  for(int j=0;j<8;j++) z[j]=0;
  return z;
}
DEV f32x4 f32x4_zero(){
  f32x4 z;
#pragma unroll
  for(int j=0;j<4;j++) z[j]=0.f;
  return z;
}
DEV f32x4 mfma16(s16x8 a, s16x8 b, f32x4 c){
  return __builtin_amdgcn_mfma_f32_16x16x32_bf16(a, b, c, 0, 0, 0);
}
// async global->LDS, 16B per lane; LDS dest must be wave-uniform (lane scatters +lane*16B)
DEV void cp16(const void* g, void* l){
  __builtin_amdgcn_global_load_lds(
      (const __attribute__((address_space(1))) unsigned int*)g,
      (__attribute__((address_space(3))) unsigned int*)l, 16, 0, 0);
}

// ---------------- problem constants ----------------
// B=4, Cin=512 (concat), H=W=64, P=9 taps, Cout=256, M = B*H*W = 16384
// padded activations: [B][66][66][C] bf16, borders zeroed -> no bounds checks
static constexpr size_t OFF_ACC_B   = 0;                         // float[16384*32]
static constexpr size_t OUT1_ACC_B  = 2097152;                   // float[16384*256]
static constexpr size_t OUT2_ACC_B  = 18874368;                  // float[16384*256]
static constexpr size_t STATS_B     = 35651584;                  // float[1024]
static constexpr size_t ZERO_BYTES  = 35655680;
static constexpr size_t XN_PAD_B    = 35655680;                  // u16[4*66*66*512]
static constexpr size_t OUT1N_PAD_B = 53497856;                  // u16[4*66*66*256]
static constexpr size_t WOFFT_B     = 62418944;                  // u16[32*4608]
static constexpr size_t WDCNT_B     = 62713856;                  // u16[256*4608]
static constexpr size_t W2T_B       = 65073152;                  // u16[256*2304]
static constexpr size_t SAMP_O_B    = 66252800;                  // int[16384*9*4]
static constexpr size_t SAMP_W_B    = 68612096;                  // float[16384*9*4]
// total ~71 MB

// ---------------- zero the padded borders (re-poisoned every call) ----------------
__global__ void k_border(u16* __restrict__ xp, u16* __restrict__ op){
  const int cid = blockIdx.x, t = threadIdx.x;       // 1040 border cells
  const int b = cid / 260, rem = cid % 260;
  int y, x;
  if(rem < 132){ y = (rem/66)*65; x = rem%66; }
  else { int r2 = rem-132; x = (r2>>6)*65; y = 1 + (r2&63); }
  const size_t cell = (size_t)(b*66+y)*66 + x;
  ((unsigned int*)(xp + cell*512))[t] = 0;           // 512 u16 = 256 u32
  if(t < 128) ((unsigned int*)(op + cell*256))[t] = 0;
}

// ---------------- NCHW fp32 (concat) -> padded NHWC bf16 ----------------
__global__ void k_x_to_nhwc(const float* __restrict__ v, const float* __restrict__ vi,
                            u16* __restrict__ xn){
  __shared__ float tile[64][65];
  const int b = blockIdx.z, c0 = blockIdx.y*64, h = blockIdx.x;
  const float* src = (c0 < 256) ? (v  + ((size_t)b*256 + c0)      *4096)
                                : (vi + ((size_t)b*256 + (c0-256))*4096);
  const int t = threadIdx.x;
#pragma unroll
  for(int k=0;k<16;k++){
    int idx = t + k*256;
    int cl = idx >> 6, wl = idx & 63;
    tile[cl][wl] = src[(size_t)cl*4096 + h*64 + wl];
  }
  __syncthreads();
#pragma unroll
  for(int k=0;k<16;k++){
    int idx = t + k*256;
    int wl = idx >> 6, cl = idx & 63;
    xn[((size_t)(b*66 + h+1)*66 + (wl+1))*512 + c0 + cl] = (u16)f2bf(tile[cl][wl]);
  }
}

// ---------------- weight repacks: OIHW fp32 -> [N][K] bf16, K = tap*C + c ----------------
__global__ void k_prep_woff(const float* __restrict__ w, u16* __restrict__ wt){
  int idx = blockIdx.x*256 + threadIdx.x;
  if(idx >= 32*4608) return;
  int n = idx / 4608, k = idx % 4608;
  int t = k >> 9, c = k & 511;
  float val = (n < 27) ? w[(size_t)(n*512 + c)*9 + t] : 0.f;
  wt[idx] = (u16)f2bf(val);
}
__global__ void k_prep_wdcn(const float* __restrict__ w, u16* __restrict__ wt){
  int idx = blockIdx.x*256 + threadIdx.x;
  if(idx >= 256*4608) return;
  int n = idx / 4608, k = idx % 4608;
  int t = k >> 9, c = k & 511;
  wt[idx] = (u16)f2bf(w[(size_t)(n*512 + c)*9 + t]);
}
__global__ void k_prep_w2(const float* __restrict__ w, u16* __restrict__ wt){
  int idx = blockIdx.x*256 + threadIdx.x;
  if(idx >= 256*2304) return;
  int n = idx / 2304, k = idx % 2304;
  int t = k >> 8, c = k & 255;
  wt[idx] = (u16)f2bf(w[(size_t)(n*256 + c)*9 + t]);
}

// ---------------- offset conv: 512ch -> 27(pad 32), fully-async implicit GEMM ----------------
// grid (256 m-tiles of 64, 3 tap-splits); block 256; K-stage 64
__global__ __launch_bounds__(256, 4) void k_conv_off(
    const u16* __restrict__ xn, const u16* __restrict__ wt, float* __restrict__ offa){
  __shared__ short A_lds[8][64][8];    // [k/8][row][8]  8KB
  __shared__ short B_lds[8][32][8];    // 4KB
  const int tid = threadIdx.x;
  const int lane = tid & 63, wid = tid >> 6;
  const int quad = lane >> 4, ln = lane & 15;
  const int m0 = blockIdx.x * 64;
  const int b = m0 >> 12;
  const int h = (m0 >> 6) & 63;
  const int ks = blockIdx.y;          // taps 3ks..3ks+2
  const int m_base = wid * 16;
  const s16x8* Ap = (const s16x8*)A_lds;
  const s16x8* Bp = (const s16x8*)B_lds;
  f32x4 acc[2];
  acc[0] = f32x4_zero(); acc[1] = f32x4_zero();

  for(int tpi=0; tpi<3; tpi++){
    const int tp = ks*3 + tpi;
    const int ty = tp/3, tx = tp - ty*3;
    // per-lane A source row (padded coords, always in-bounds)
    const u16* arow = xn + ((size_t)(b*66 + h+ty)*66 + lane + tx)*512;
    const u16* brow = wt + (size_t)(lane & 31)*4608 + tp*512 + (wid*2 + (lane>>5))*8;
    for(int s=0; s<8; s++){
      const int cb = s*64;
      cp16(arow + cb + (wid*2)*8,     &A_lds[wid*2][0][0]);
      cp16(arow + cb + (wid*2+1)*8,   &A_lds[wid*2+1][0][0]);
      cp16(brow + cb,                 &B_lds[wid*2][0][0]);
      __syncthreads();
#pragma unroll
      for(int cc=0; cc<2; cc++){
        const int s2 = cc*4 + quad;
        s16x8 a  = Ap[s2*64 + m_base + ln];
        s16x8 b0 = Bp[s2*32 + ln];
        s16x8 b1 = Bp[s2*32 + 16 + ln];
        acc[0] = mfma16(a, b0, acc[0]);
        acc[1] = mfma16(a, b1, acc[1]);
      }
      __syncthreads();
    }
  }
#pragma unroll
  for(int nf=0;nf<2;nf++){
    const int col = nf*16 + ln;
#pragma unroll
    for(int i=0;i<4;i++){
      const int row = m_base + quad*4 + i;
      unsafeAtomicAdd(offa + (size_t)(m0+row)*32 + col, acc[nf][i]);
    }
  }
}

// ---------------- sampler: precompute bilinear taps (padded offsets + weights) ----------------
__global__ void k_sampler(const float* __restrict__ offa, const float* __restrict__ boff,
                          int* __restrict__ so, float* __restrict__ sw){
  const int idx = blockIdx.x*256 + threadIdx.x;
  if(idx >= 16384*9) return;
  const int m = idx / 9, tp = idx - m*9;
  const int b = m >> 12, h = (m >> 6) & 63, w = m & 63;
  const float* orow = offa + (size_t)m*32;
  float dy = orow[2*tp]   + boff[2*tp];
  float dx = orow[2*tp+1] + boff[2*tp+1];
  float mz = orow[18+tp]  + boff[18+tp];
  float mk = 1.f / (1.f + expf(-mz));
  float ypos = (float)(h - 1 + tp/3) + dy;
  float xpos = (float)(w - 1 + tp%3) + dx;
  float y0f = floorf(ypos), x0f = floorf(xpos);
  float ly = ypos - y0f, lx = xpos - x0f;
  int y0 = (int)y0f, x0 = (int)x0f;
#pragma unroll
  for(int k=0;k<4;k++){
    int ddy = k >> 1, ddx = k & 1;
    int yi = y0 + ddy, xi = x0 + ddx;
    bool vv = (yi >= 0) & (yi < 64) & (xi >= 0) & (xi < 64);
    float wk = (ddy ? ly : 1.f-ly) * (ddx ? lx : 1.f-lx) * mk;
    if(!vv) wk = 0.f;
    int yc = yi < 0 ? 0 : (yi > 63 ? 63 : yi);
    int xc = xi < 0 ? 0 : (xi > 63 ? 63 : xi);
    so[(size_t)idx*4 + k] = ((b*66 + yc+1)*66 + xc+1) << 9;   // *512 (padded)
    sw[(size_t)idx*4 + k] = wk;
  }
}

// ---------------- DCN main: bilinear-sample A, async B, GEMM vs w_dcn ----------------
// grid (256 m-tiles of 64, 3 tap-splits); block 256; 64m x 256n tile, K-stage 64
__global__ __launch_bounds__(256, 3) void k_dcn(
    const u16* __restrict__ xn, const u16* __restrict__ wt,
    const int* __restrict__ so, const float* __restrict__ sw,
    float* __restrict__ outa){
  __shared__ short A_lds[8][64][8];    // 8KB
  __shared__ short B_lds[8][256][8];   // 32KB
  const int tid = threadIdx.x;
  const int lane = tid & 63, wid = tid >> 6;
  const int quad = lane >> 4, ln = lane & 15;
  const int m0 = blockIdx.x * 64;
  const int ks = blockIdx.y;           // taps 3ks..3ks+2
  const int m_base = (wid >> 1)*32, n_base = (wid & 1)*128;
  const int r = tid >> 2, sub = tid & 3;
  const int nw = wid * 64;
  const s16x8* Ap = (const s16x8*)A_lds;
  const s16x8* Bp = (const s16x8*)B_lds;
  f32x4 acc[2][8];
#pragma unroll
  for(int mf=0;mf<2;mf++)
#pragma unroll
    for(int nf=0;nf<8;nf++) acc[mf][nf] = f32x4_zero();

  for(int tpi=0; tpi<3; tpi++){
    const int tp = ks*3 + tpi;
    const int4   po = *(const int4*)  (so + ((size_t)(m0+r)*9 + tp)*4);
    const float4 pw = *(const float4*)(sw + ((size_t)(m0+r)*9 + tp)*4);
    const u16* a0p = xn + po.x + sub*8;
    const u16* a1p = xn + po.y + sub*8;
    const u16* a2p = xn + po.z + sub*8;
    const u16* a3p = xn + po.w + sub*8;
    const u16* bsrc = wt + (size_t)(nw + lane)*4608 + tp*512;

    for(int s=0; s<8; s++){
      const int c0 = s*64;
      // A gather (VGPR path: weighted combine)
      s16x8 v00 = *(const s16x8*)(a0p + c0);
      s16x8 v01 = *(const s16x8*)(a1p + c0);
      s16x8 v02 = *(const s16x8*)(a2p + c0);
      s16x8 v03 = *(const s16x8*)(a3p + c0);
      s16x8 v10 = *(const s16x8*)(a0p + c0 + 32);
      s16x8 v11 = *(const s16x8*)(a1p + c0 + 32);
      s16x8 v12 = *(const s16x8*)(a2p + c0 + 32);
      s16x8 v13 = *(const s16x8*)(a3p + c0 + 32);
      // B async while A combine runs
#pragma unroll
      for(int s2=0; s2<8; s2++)
        cp16(bsrc + c0 + s2*8, &B_lds[s2][nw][0]);
      s16x8 pk0, pk1;
#pragma unroll
      for(int j=0;j<8;j++){
        float f0 = pw.x * bf2f(v00[j]);
        f0 = fmaf(pw.y, bf2f(v01[j]), f0);
        f0 = fmaf(pw.z, bf2f(v02[j]), f0);
        f0 = fmaf(pw.w, bf2f(v03[j]), f0);
        pk0[j] = f2bf(f0);
        float f1 = pw.x * bf2f(v10[j]);
        f1 = fmaf(pw.y, bf2f(v11[j]), f1);
        f1 = fmaf(pw.z, bf2f(v12[j]), f1);
        f1 = fmaf(pw.w, bf2f(v13[j]), f1);
        pk1[j] = f2bf(f1);
      }
      *(s16x8*)(&A_lds[sub][r][0])     = pk0;
      *(s16x8*)(&A_lds[sub+4][r][0])   = pk1;
      __syncthreads();
#pragma unroll
      for(int cc=0; cc<2; cc++){
        const int s2 = cc*4 + quad;
        s16x8 a0 = Ap[s2*64 + m_base + ln];
        s16x8 a1 = Ap[s2*64 + m_base + 16 + ln];
        s16x8 bfr[8];
#pragma unroll
        for(int nf=0;nf<8;nf++) bfr[nf] = Bp[s2*256 + n_base + nf*16 + ln];
#pragma unroll
        for(int nf=0;nf<8;nf++){
          acc[0][nf] = mfma16(a0, bfr[nf], acc[0][nf]);
          acc[1][nf] = mfma16(a1, bfr[nf], acc[1][nf]);
        }
      }
      __syncthreads();
    }
  }
#pragma unroll
  for(int mf=0;mf<2;mf++)
#pragma unroll
    for(int nf=0;nf<8;nf++){
      const int col = n_base + nf*16 + ln;
#pragma unroll
      for(int i=0;i<4;i++){
        const int row = m_base + mf*16 + quad*4 + i;
        unsafeAtomicAdd(outa + (size_t)(m0+row)*256 + col, acc[mf][nf][i]);
      }
    }
}

// ---------------- conv2: 256 -> 256, fully-async implicit GEMM on padded out1 ----------------
// grid (256 m-tiles of 64, 3 tap-splits); block 256; 64m x 256n, K-stage 64
__global__ __launch_bounds__(256, 3) void k_conv2(
    const u16* __restrict__ a_in, const u16* __restrict__ wt, float* __restrict__ outa){
  __shared__ short A_lds[8][64][8];    // 8KB
  __shared__ short B_lds[8][256][8];   // 32KB
  const int tid = threadIdx.x;
  const int lane = tid & 63, wid = tid >> 6;
  const int quad = lane >> 4, ln = lane & 15;
  const int m0 = blockIdx.x * 64;
  const int b = m0 >> 12;
  const int h = (m0 >> 6) & 63;
  const int ks = blockIdx.y;
  const int m_base = (wid >> 1)*32, n_base = (wid & 1)*128;
  const int nw = wid * 64;
  const s16x8* Ap = (const s16x8*)A_lds;
  const s16x8* Bp = (const s16x8*)B_lds;
  f32x4 acc[2][8];
#pragma unroll
  for(int mf=0;mf<2;mf++)
#pragma unroll
    for(int nf=0;nf<8;nf++) acc[mf][nf] = f32x4_zero();

  for(int tpi=0; tpi<3; tpi++){
    const int tp = ks*3 + tpi;
    const int ty = tp/3, tx = tp - ty*3;
    const u16* arow = a_in + ((size_t)(b*66 + h+ty)*66 + lane + tx)*256;
    const u16* bsrc = wt + (size_t)(nw + lane)*2304 + tp*256;
    for(int s=0; s<4; s++){           // K=256 per tap, 4 stages of 64
      const int c0 = s*64;
      cp16(arow + c0 + wid*8,       &A_lds[wid][0][0]);
      cp16(arow + c0 + (wid+4)*8,   &A_lds[wid+4][0][0]);
#pragma unroll
      for(int s2=0; s2<8; s2++)
        cp16(bsrc + c0 + s2*8, &B_lds[s2][nw][0]);
      __syncthreads();
#pragma unroll
      for(int cc=0; cc<2; cc++){
        const int s2 = cc*4 + quad;
        s16x8 a0 = Ap[s2*64 + m_base + ln];
        s16x8 a1 = Ap[s2*64 + m_base + 16 + ln];
        s16x8 bfr[8];
#pragma unroll
        for(int nf=0;nf<8;nf++) bfr[nf] = Bp[s2*256 + n_base + nf*16 + ln];
#pragma unroll
        for(int nf=0;nf<8;nf++){
          acc[0][nf] = mfma16(a0, bfr[nf], acc[0][nf]);
          acc[1][nf] = mfma16(a1, bfr[nf], acc[1][nf]);
        }
      }
      __syncthreads();
    }
  }
#pragma unroll
  for(int mf=0;mf<2;mf++)
#pragma unroll
    for(int nf=0;nf<8;nf++){
      const int col = n_base + nf*16 + ln;
#pragma unroll
      for(int i=0;i<4;i++){
        const int row = m_base + mf*16 + quad*4 + i;
        unsafeAtomicAdd(outa + (size_t)(m0+row)*256 + col, acc[mf][nf][i]);
      }
    }
}

// ---------------- BN stats: per-channel sum/sumsq over M=16384 ----------------
__global__ void k_stats(const float* __restrict__ acc, float* __restrict__ sum,
                        float* __restrict__ sq){
  const int m0 = blockIdx.x*64;
  const int c = threadIdx.x;
  float s = 0.f, q = 0.f;
  for(int i=0;i<64;i++){
    float v = acc[(size_t)(m0+i)*256 + c];
    s += v; q += v*v;
  }
  unsafeAtomicAdd(sum + c, s);
  unsafeAtomicAdd(sq + c, q);
}

// ---------------- BN1 + ReLU -> padded bf16 NHWC ----------------
__global__ void k_bn1(const float* __restrict__ acc, const float* __restrict__ sum,
                      const float* __restrict__ sq, const float* __restrict__ g,
                      const float* __restrict__ bt, u16* __restrict__ o){
  __shared__ float sc[256], sh[256];
  const int t = threadIdx.x;
  {
    float mean = sum[t] * (1.f/16384.f);
    float var  = sq[t] * (1.f/16384.f) - mean*mean;
    float rstd = rsqrtf(var + 1e-5f);
    float s = g[t] * rstd;
    sc[t] = s; sh[t] = bt[t] - mean*s;
  }
  __syncthreads();
  const int c4 = (t & 63) * 4;
  const float s0 = sc[c4], s1 = sc[c4+1], s2 = sc[c4+2], s3 = sc[c4+3];
  const float h0 = sh[c4], h1 = sh[c4+1], h2 = sh[c4+2], h3 = sh[c4+3];
#pragma unroll
  for(int k=0;k<4;k++){
    int m = blockIdx.x*16 + k*4 + (t>>6);
    int b = m >> 12, hh = (m >> 6) & 63, ww = m & 63;
    const float4 v = *(const float4*)(acc + (size_t)m*256 + c4);
    unsigned int lo = (unsigned int)(u16)f2bf(fmaxf(0.f, v.x*s0 + h0))
                    | ((unsigned int)(u16)f2bf(fmaxf(0.f, v.y*s1 + h1)) << 16);
    unsigned int hi = (unsigned int)(u16)f2bf(fmaxf(0.f, v.z*s2 + h2))
                    | ((unsigned int)(u16)f2bf(fmaxf(0.f, v.w*s3 + h3)) << 16);
    uint2 pr; pr.x = lo; pr.y = hi;
    *(uint2*)(o + ((size_t)(b*66 + hh+1)*66 + ww+1)*256 + c4) = pr;
  }
}

// ---------------- BN2 + ReLU + NHWC->NCHW fp32 output ----------------
__global__ void k_bn2_out(const float* __restrict__ acc, const float* __restrict__ sum,
                          const float* __restrict__ sq, const float* __restrict__ g,
                          const float* __restrict__ bt, float* __restrict__ out){
  __shared__ float tile[64][65];
  __shared__ float sc[64], sh[64];
  const int t = threadIdx.x;
  const int b = blockIdx.z, c0 = blockIdx.y*64, hw0 = blockIdx.x*64;
  if(t < 64){
    int c = c0 + t;
    float mean = sum[c] * (1.f/16384.f);
    float var  = sq[c] * (1.f/16384.f) - mean*mean;
    float rstd = rsqrtf(var + 1e-5f);
    float s = g[c] * rstd;
    sc[t] = s; sh[t] = bt[c] - mean*s;
  }
  __syncthreads();
#pragma unroll
  for(int k=0;k<16;k++){
    int idx = t + k*256;
    int wl = idx >> 6, cl = idx & 63;
    float v = acc[(size_t)((b<<12) + hw0 + wl)*256 + c0 + cl];
    tile[wl][cl] = fmaxf(0.f, v*sc[cl] + sh[cl]);
  }
  __syncthreads();
#pragma unroll
  for(int k=0;k<16;k++){
    int idx = t + k*256;
    int cl = idx >> 6, wl = idx & 63;
    out[(size_t)(b*256 + c0 + cl)*4096 + hw0 + wl] = tile[wl][cl];
  }
}

extern "C" void kernel_launch(void* const* d_in, const int* in_sizes, int n_in,
                              void* d_out, int out_size, void* d_ws, size_t ws_size,
                              hipStream_t stream){
  const float* in_v  = (const float*)d_in[0];
  const float* in_i  = (const float*)d_in[1];
  const float* w_off = (const float*)d_in[2];
  const float* b_off = (const float*)d_in[3];
  const float* w_dcn = (const float*)d_in[4];
  const float* g1    = (const float*)d_in[5];
  const float* bt1   = (const float*)d_in[6];
  const float* w2    = (const float*)d_in[7];
  const float* g2    = (const float*)d_in[8];
  const float* bt2   = (const float*)d_in[9];
  float* out = (float*)d_out;
  char* ws = (char*)d_ws;

  float* off_acc  = (float*)(ws + OFF_ACC_B);
  float* out1_acc = (float*)(ws + OUT1_ACC_B);
  float* out2_acc = (float*)(ws + OUT2_ACC_B);
  float* stats    = (float*)(ws + STATS_B);
  float* sum1 = stats,       *sq1 = stats + 256;
  float* sum2 = stats + 512, *sq2 = stats + 768;
  u16* xn_pad    = (u16*)(ws + XN_PAD_B);
  u16* out1n_pad = (u16*)(ws + OUT1N_PAD_B);
  u16* wofft = (u16*)(ws + WOFFT_B);
  u16* wdcnt = (u16*)(ws + WDCNT_B);
  u16* w2t   = (u16*)(ws + W2T_B);
  int*   samp_o = (int*)(ws + SAMP_O_B);
  float* samp_w = (float*)(ws + SAMP_W_B);

  hipMemsetAsync(ws, 0, ZERO_BYTES, stream);
  k_border<<<1040, 256, 0, stream>>>(xn_pad, out1n_pad);
  k_x_to_nhwc<<<dim3(64,8,4), 256, 0, stream>>>(in_v, in_i, xn_pad);
  k_prep_woff<<<576, 256, 0, stream>>>(w_off, wofft);
  k_prep_wdcn<<<4608, 256, 0, stream>>>(w_dcn, wdcnt);
  k_prep_w2<<<2304, 256, 0, stream>>>(w2, w2t);
  k_conv_off<<<dim3(256,3), 256, 0, stream>>>(xn_pad, wofft, off_acc);
  k_sampler<<<576, 256, 0, stream>>>(off_acc, b_off, samp_o, samp_w);
  k_dcn<<<dim3(256,3), 256, 0, stream>>>(xn_pad, wdcnt, samp_o, samp_w, out1_acc);
  k_stats<<<256, 256, 0, stream>>>(out1_acc, sum1, sq1);
  k_bn1<<<1024, 256, 0, stream>>>(out1_acc, sum1, sq1, g1, bt1, out1n_pad);
  k_conv2<<<dim3(256,3), 256, 0, stream>>>(out1n_pad, w2t, out2_acc);
  k_stats<<<256, 256, 0, stream>>>(out2_acc, sum2, sq2);
  k_bn2_out<<<dim3(64,4,4), 256, 0, stream>>>(out2_acc, sum2, sq2, g2, bt2, out);
}

// Round 3
// 407.499 us; speedup vs baseline: 1.0088x; 1.0088x over previous
//
#include <hip/hip_runtime.h>
#include <cstdint>
#include <cstddef>

typedef unsigned short u16;
typedef __attribute__((ext_vector_type(8))) short s16x8;
typedef __attribute__((ext_vector_type(4))) float f32x4;

#define DEV __device__ __forceinline__

DEV float bf2f(short u){
  union { unsigned int i; float f; } v;
  v.i = ((unsigned int)(u16)u) << 16;
  return v.f;
}
DEV short f2bf(float f){
  union { float f; unsigned int i; } v; v.f = f;
  unsigned int u = v.i;
  u += 0x7fffu + ((u >> 16) & 1u);   // RNE
  return (short)(u >> 16);
}
DEV f32x4 f32x4_zero(){
  f32x4 z;
#pragma unroll
  for(int j=0;j<4;j++) z[j]=0.f;
  return z;
}
DEV f32x4 mfma16(s16x8 a, s16x8 b, f32x4 c){
  return __builtin_amdgcn_mfma_f32_16x16x32_bf16(a, b, c, 0, 0, 0);
}
// async global->LDS, 16B/lane; global addr is per-lane, LDS dest = uniform base + lane*16B
DEV void cp16(const void* g, void* l){
  __builtin_amdgcn_global_load_lds(
      (const __attribute__((address_space(1))) unsigned int*)g,
      (__attribute__((address_space(3))) unsigned int*)l, 16, 0, 0);
}

// ---------------- problem constants ----------------
// B=4, Cin=512 (concat), H=W=64, P=9 taps, Cout=256, M = B*H*W = 16384
// padded activations: [B][66][66][C] bf16, borders zeroed -> no bounds checks
static constexpr size_t OFF_ACC_B   = 0;                         // float[16384*32]
static constexpr size_t OUT1_ACC_B  = 2097152;                   // float[16384*256]
static constexpr size_t OUT2_ACC_B  = 18874368;                  // float[16384*256]
static constexpr size_t STATS_B     = 35651584;                  // float[1024]
static constexpr size_t ZERO_BYTES  = 35655680;
static constexpr size_t XN_PAD_B    = 35655680;                  // u16[4*66*66*512]
static constexpr size_t OUT1N_PAD_B = 53497856;                  // u16[4*66*66*256]
static constexpr size_t WOFFT_B     = 62418944;                  // u16[9*64*32*8]
static constexpr size_t WDCNT_B     = 62713856;                  // u16[9*64*256*8]
static constexpr size_t W2T_B       = 65073152;                  // u16[9*32*256*8]
static constexpr size_t SAMP_O_B    = 66252800;                  // int[16384*9*4]
static constexpr size_t SAMP_W_B    = 68612096;                  // float[16384*9*4]

// ---------------- zero the padded borders (ws re-poisoned every call) ----------------
__global__ void k_border(u16* __restrict__ xp, u16* __restrict__ op){
  const int cid = blockIdx.x, t = threadIdx.x;       // 1040 border cells
  const int b = cid / 260, rem = cid % 260;
  int y, x;
  if(rem < 132){ y = (rem/66)*65; x = rem%66; }
  else { int r2 = rem-132; x = (r2>>6)*65; y = 1 + (r2&63); }
  const size_t cell = (size_t)(b*66+y)*66 + x;
  ((unsigned int*)(xp + cell*512))[t] = 0;
  if(t < 128) ((unsigned int*)(op + cell*256))[t] = 0;
}

// ---------------- NCHW fp32 (concat) -> padded NHWC bf16 ----------------
__global__ void k_x_to_nhwc(const float* __restrict__ v, const float* __restrict__ vi,
                            u16* __restrict__ xn){
  __shared__ float tile[64][65];
  const int b = blockIdx.z, c0 = blockIdx.y*64, h = blockIdx.x;
  const float* src = (c0 < 256) ? (v  + ((size_t)b*256 + c0)      *4096)
                                : (vi + ((size_t)b*256 + (c0-256))*4096);
  const int t = threadIdx.x;
#pragma unroll
  for(int k=0;k<16;k++){
    int idx = t + k*256;
    int cl = idx >> 6, wl = idx & 63;
    tile[cl][wl] = src[(size_t)cl*4096 + h*64 + wl];
  }
  __syncthreads();
#pragma unroll
  for(int k=0;k<16;k++){
    int idx = t + k*256;
    int wl = idx >> 6, cl = idx & 63;
    xn[((size_t)(b*66 + h+1)*66 + (wl+1))*512 + c0 + cl] = (u16)f2bf(tile[cl][wl]);
  }
}

// ---------------- weight repacks into [tap][kchunk][n][8] bf16 (coalesced B staging) ----------------
__global__ void k_prep_woff(const float* __restrict__ w, u16* __restrict__ wt){
  int i = blockIdx.x*256 + threadIdx.x;        // 9*64*32*8 = 147456
  if(i >= 147456) return;
  int j = i & 7, n = (i>>3) & 31, kcp = i>>8;
  int kc = kcp & 63, tp = kcp >> 6;
  int c = kc*8 + j;
  float val = (n < 27) ? w[(size_t)(n*512 + c)*9 + tp] : 0.f;
  wt[i] = (u16)f2bf(val);
}
__global__ void k_prep_wdcn(const float* __restrict__ w, u16* __restrict__ wt){
  int i = blockIdx.x*256 + threadIdx.x;        // 9*64*256*8 = 1179648
  if(i >= 1179648) return;
  int j = i & 7, n = (i>>3) & 255, kcp = i>>11;
  int kc = kcp & 63, tp = kcp >> 6;
  int c = kc*8 + j;
  wt[i] = (u16)f2bf(w[(size_t)(n*512 + c)*9 + tp]);
}
__global__ void k_prep_w2(const float* __restrict__ w, u16* __restrict__ wt){
  int i = blockIdx.x*256 + threadIdx.x;        // 9*32*256*8 = 589824
  if(i >= 589824) return;
  int j = i & 7, n = (i>>3) & 255, kcp = i>>11;
  int kc = kcp & 31, tp = kcp >> 5;
  int c = kc*8 + j;
  wt[i] = (u16)f2bf(w[(size_t)(n*256 + c)*9 + tp]);
}

// ---------------- offset conv: 512ch -> 27(pad 32); dbuf pipeline, K=32 stages ----------------
// 144 global stages (9 taps x 16); grid (256 m-tiles, 6 k-splits of 24 stages)
__global__ __launch_bounds__(256, 6) void k_conv_off(
    const u16* __restrict__ xn, const u16* __restrict__ wt, float* __restrict__ offa){
  __shared__ short A[2][4][64][8];   // [buf][chunk][row][8]  8KB
  __shared__ short B[2][4][32][8];   // 4KB
  const int tid = threadIdx.x;
  const int lane = tid & 63, wid = tid >> 6;
  const int quad = lane >> 4, ln = lane & 15;
  const int m0 = blockIdx.x * 64;
  const int b = m0 >> 12, h = (m0 >> 6) & 63;
  const int gst0 = blockIdx.y * 24;
  const int m_base = wid * 16;
  f32x4 acc0 = f32x4_zero(), acc1 = f32x4_zero();

  // prologue fill stage gst0 -> buf 0
  {
    const int tp = gst0 >> 4, s = gst0 & 15;
    const int ty = tp/3, tx = tp - ty*3;
    cp16(xn + ((size_t)(b*66 + h+ty)*66 + lane + tx)*512 + s*32 + wid*8, &A[0][wid][0][0]);
    if(wid < 2)
      cp16(wt + ((size_t)tp*64 + s*4)*256 + wid*512 + lane*8, (short*)&B[0][0][0][0] + wid*512);
  }
  __syncthreads();

  int buf = 0;
  for(int it=0; it<24; it++){
    const int nb = buf ^ 1;
    if(it < 23){
      const int gn = gst0 + it + 1;
      const int tp = gn >> 4, s = gn & 15;
      const int ty = tp/3, tx = tp - ty*3;
      cp16(xn + ((size_t)(b*66 + h+ty)*66 + lane + tx)*512 + s*32 + wid*8, &A[nb][wid][0][0]);
      if(wid < 2)
        cp16(wt + ((size_t)tp*64 + s*4)*256 + wid*512 + lane*8, (short*)&B[nb][0][0][0] + wid*512);
    }
    const s16x8* Ap = (const s16x8*)&A[buf][0][0][0];
    const s16x8* Bp = (const s16x8*)&B[buf][0][0][0];
    s16x8 a  = Ap[quad*64 + m_base + ln];
    s16x8 b0 = Bp[quad*32 + ln];
    s16x8 b1 = Bp[quad*32 + 16 + ln];
    acc0 = mfma16(a, b0, acc0);
    acc1 = mfma16(a, b1, acc1);
    __syncthreads();
    buf = nb;
  }
#pragma unroll
  for(int nf=0;nf<2;nf++){
    const f32x4 v = nf ? acc1 : acc0;
    const int col = nf*16 + ln;
#pragma unroll
    for(int i=0;i<4;i++){
      const int row = m_base + quad*4 + i;
      unsafeAtomicAdd(offa + (size_t)(m0+row)*32 + col, v[i]);
    }
  }
}

// ---------------- sampler: precompute bilinear taps (padded offsets + weights) ----------------
__global__ void k_sampler(const float* __restrict__ offa, const float* __restrict__ boff,
                          int* __restrict__ so, float* __restrict__ sw){
  const int idx = blockIdx.x*256 + threadIdx.x;
  if(idx >= 16384*9) return;
  const int m = idx / 9, tp = idx - m*9;
  const int b = m >> 12, h = (m >> 6) & 63, w = m & 63;
  const float* orow = offa + (size_t)m*32;
  float dy = orow[2*tp]   + boff[2*tp];
  float dx = orow[2*tp+1] + boff[2*tp+1];
  float mz = orow[18+tp]  + boff[18+tp];
  float mk = 1.f / (1.f + expf(-mz));
  float ypos = (float)(h - 1 + tp/3) + dy;
  float xpos = (float)(w - 1 + tp%3) + dx;
  float y0f = floorf(ypos), x0f = floorf(xpos);
  float ly = ypos - y0f, lx = xpos - x0f;
  int y0 = (int)y0f, x0 = (int)x0f;
#pragma unroll
  for(int k=0;k<4;k++){
    int ddy = k >> 1, ddx = k & 1;
    int yi = y0 + ddy, xi = x0 + ddx;
    bool vv = (yi >= 0) & (yi < 64) & (xi >= 0) & (xi < 64);
    float wk = (ddy ? ly : 1.f-ly) * (ddx ? lx : 1.f-lx) * mk;
    if(!vv) wk = 0.f;
    int yc = yi < 0 ? 0 : (yi > 63 ? 63 : yi);
    int xc = xi < 0 ? 0 : (xi > 63 ? 63 : xi);
    so[(size_t)idx*4 + k] = ((b*66 + yc+1)*66 + xc+1) << 9;   // *512 (padded)
    sw[(size_t)idx*4 + k] = wk;
  }
}

// ---------------- DCN main: dbuf pipeline, gather-A (VGPR) + packed-B (cp16), K=32 ----------------
// 144 global stages (9 taps x 16); grid (256 m-tiles, 6 k-splits of 24 stages); tile 64m x 256n
__global__ __launch_bounds__(256, 4) void k_dcn(
    const u16* __restrict__ xn, const u16* __restrict__ wt,
    const int* __restrict__ so, const float* __restrict__ sw,
    float* __restrict__ outa){
  __shared__ short A[2][4][64][8];    // 8KB  [buf][chunk][row][8]
  __shared__ short B[2][4][256][8];   // 32KB [buf][chunk][n][8]
  const int tid = threadIdx.x;
  const int lane = tid & 63, wid = tid >> 6;
  const int quad = lane >> 4, ln = lane & 15;
  const int m0 = blockIdx.x * 64;
  const int gst0 = blockIdx.y * 24;
  const int m_base = (wid >> 1)*32, n_base = (wid & 1)*128;
  const int r = tid >> 2, sub = tid & 3;
  f32x4 acc[2][8];
#pragma unroll
  for(int mf=0;mf<2;mf++)
#pragma unroll
    for(int nf=0;nf<8;nf++) acc[mf][nf] = f32x4_zero();

  int4 po; float4 pw;
  s16x8 g0, g1, g2, g3;

  // prologue: fill stage gst0 into buf 0
  {
    const int tp = gst0 >> 4, s = gst0 & 15;
    po = *(const int4*)  (so + ((size_t)(m0+r)*9 + tp)*4);
    pw = *(const float4*)(sw + ((size_t)(m0+r)*9 + tp)*4);
    const u16* bs = wt + ((size_t)tp*64 + s*4)*2048 + (wid*4)*512 + lane*8;
    short* bd = (short*)&B[0][0][0][0] + (wid*4)*512;
#pragma unroll
    for(int i=0;i<4;i++) cp16(bs + i*512, bd + i*512);
    const int c0 = s*32 + sub*8;
    g0 = *(const s16x8*)(xn + po.x + c0);
    g1 = *(const s16x8*)(xn + po.y + c0);
    g2 = *(const s16x8*)(xn + po.z + c0);
    g3 = *(const s16x8*)(xn + po.w + c0);
    s16x8 pk;
#pragma unroll
    for(int j=0;j<8;j++){
      float f = pw.x * bf2f(g0[j]);
      f = fmaf(pw.y, bf2f(g1[j]), f);
      f = fmaf(pw.z, bf2f(g2[j]), f);
      f = fmaf(pw.w, bf2f(g3[j]), f);
      pk[j] = f2bf(f);
    }
    *(s16x8*)(&A[0][sub][r][0]) = pk;
  }
  __syncthreads();

  int buf = 0;
  for(int it=0; it<24; it++){
    const int nb = buf ^ 1;
    if(it < 23){
      const int gn = gst0 + it + 1;
      const int tp = gn >> 4, s = gn & 15;
      if((gn & 15) == 0){
        po = *(const int4*)  (so + ((size_t)(m0+r)*9 + tp)*4);
        pw = *(const float4*)(sw + ((size_t)(m0+r)*9 + tp)*4);
      }
      const u16* bs = wt + ((size_t)tp*64 + s*4)*2048 + (wid*4)*512 + lane*8;
      short* bd = (short*)&B[nb][0][0][0] + (wid*4)*512;
#pragma unroll
      for(int i=0;i<4;i++) cp16(bs + i*512, bd + i*512);
      const int c0 = s*32 + sub*8;
      g0 = *(const s16x8*)(xn + po.x + c0);
      g1 = *(const s16x8*)(xn + po.y + c0);
      g2 = *(const s16x8*)(xn + po.z + c0);
      g3 = *(const s16x8*)(xn + po.w + c0);
    }
    // compute current stage from buf
    {
      const s16x8* Ap = (const s16x8*)&A[buf][0][0][0];
      const s16x8* Bp = (const s16x8*)&B[buf][0][0][0];
      s16x8 a0 = Ap[quad*64 + m_base + ln];
      s16x8 a1 = Ap[quad*64 + m_base + 16 + ln];
#pragma unroll
      for(int nf=0;nf<8;nf++){
        s16x8 bf = Bp[quad*256 + n_base + nf*16 + ln];
        acc[0][nf] = mfma16(a0, bf, acc[0][nf]);
        acc[1][nf] = mfma16(a1, bf, acc[1][nf]);
      }
    }
    if(it < 23){
      s16x8 pk;
#pragma unroll
      for(int j=0;j<8;j++){
        float f = pw.x * bf2f(g0[j]);
        f = fmaf(pw.y, bf2f(g1[j]), f);
        f = fmaf(pw.z, bf2f(g2[j]), f);
        f = fmaf(pw.w, bf2f(g3[j]), f);
        pk[j] = f2bf(f);
      }
      *(s16x8*)(&A[nb][sub][r][0]) = pk;
    }
    __syncthreads();
    buf = nb;
  }
#pragma unroll
  for(int mf=0;mf<2;mf++)
#pragma unroll
    for(int nf=0;nf<8;nf++){
      const int col = n_base + nf*16 + ln;
#pragma unroll
      for(int i=0;i<4;i++){
        const int row = m_base + mf*16 + quad*4 + i;
        unsafeAtomicAdd(outa + (size_t)(m0+row)*256 + col, acc[mf][nf][i]);
      }
    }
}

// ---------------- conv2: 256 -> 256, dbuf all-cp16 pipeline, K=32 stages ----------------
// 72 global stages (9 taps x 8); grid (256 m-tiles, 6 k-splits of 12 stages)
__global__ __launch_bounds__(256, 4) void k_conv2(
    const u16* __restrict__ a_in, const u16* __restrict__ wt, float* __restrict__ outa){
  __shared__ short A[2][4][64][8];    // 8KB
  __shared__ short B[2][4][256][8];   // 32KB
  const int tid = threadIdx.x;
  const int lane = tid & 63, wid = tid >> 6;
  const int quad = lane >> 4, ln = lane & 15;
  const int m0 = blockIdx.x * 64;
  const int b = m0 >> 12, h = (m0 >> 6) & 63;
  const int gst0 = blockIdx.y * 12;
  const int m_base = (wid >> 1)*32, n_base = (wid & 1)*128;
  f32x4 acc[2][8];
#pragma unroll
  for(int mf=0;mf<2;mf++)
#pragma unroll
    for(int nf=0;nf<8;nf++) acc[mf][nf] = f32x4_zero();

  // prologue
  {
    const int tp = gst0 >> 3, s = gst0 & 7;
    const int ty = tp/3, tx = tp - ty*3;
    cp16(a_in + ((size_t)(b*66 + h+ty)*66 + lane + tx)*256 + s*32 + wid*8, &A[0][wid][0][0]);
    const u16* bs = wt + ((size_t)tp*32 + s*4)*2048 + (wid*4)*512 + lane*8;
    short* bd = (short*)&B[0][0][0][0] + (wid*4)*512;
#pragma unroll
    for(int i=0;i<4;i++) cp16(bs + i*512, bd + i*512);
  }
  __syncthreads();

  int buf = 0;
  for(int it=0; it<12; it++){
    const int nb = buf ^ 1;
    if(it < 11){
      const int gn = gst0 + it + 1;
      const int tp = gn >> 3, s = gn & 7;
      const int ty = tp/3, tx = tp - ty*3;
      cp16(a_in + ((size_t)(b*66 + h+ty)*66 + lane + tx)*256 + s*32 + wid*8, &A[nb][wid][0][0]);
      const u16* bs = wt + ((size_t)tp*32 + s*4)*2048 + (wid*4)*512 + lane*8;
      short* bd = (short*)&B[nb][0][0][0] + (wid*4)*512;
#pragma unroll
      for(int i=0;i<4;i++) cp16(bs + i*512, bd + i*512);
    }
    const s16x8* Ap = (const s16x8*)&A[buf][0][0][0];
    const s16x8* Bp = (const s16x8*)&B[buf][0][0][0];
    s16x8 a0 = Ap[quad*64 + m_base + ln];
    s16x8 a1 = Ap[quad*64 + m_base + 16 + ln];
#pragma unroll
    for(int nf=0;nf<8;nf++){
      s16x8 bf = Bp[quad*256 + n_base + nf*16 + ln];
      acc[0][nf] = mfma16(a0, bf, acc[0][nf]);
      acc[1][nf] = mfma16(a1, bf, acc[1][nf]);
    }
    __syncthreads();
    buf = nb;
  }
#pragma unroll
  for(int mf=0;mf<2;mf++)
#pragma unroll
    for(int nf=0;nf<8;nf++){
      const int col = n_base + nf*16 + ln;
#pragma unroll
      for(int i=0;i<4;i++){
        const int row = m_base + mf*16 + quad*4 + i;
        unsafeAtomicAdd(outa + (size_t)(m0+row)*256 + col, acc[mf][nf][i]);
      }
    }
}

// ---------------- BN stats: per-channel sum/sumsq over M=16384 ----------------
__global__ void k_stats(const float* __restrict__ acc, float* __restrict__ sum,
                        float* __restrict__ sq){
  const int m0 = blockIdx.x*64;
  const int c = threadIdx.x;
  float s = 0.f, q = 0.f;
  for(int i=0;i<64;i++){
    float v = acc[(size_t)(m0+i)*256 + c];
    s += v; q += v*v;
  }
  unsafeAtomicAdd(sum + c, s);
  unsafeAtomicAdd(sq + c, q);
}

// ---------------- BN1 + ReLU -> padded bf16 NHWC ----------------
__global__ void k_bn1(const float* __restrict__ acc, const float* __restrict__ sum,
                      const float* __restrict__ sq, const float* __restrict__ g,
                      const float* __restrict__ bt, u16* __restrict__ o){
  __shared__ float sc[256], sh[256];
  const int t = threadIdx.x;
  {
    float mean = sum[t] * (1.f/16384.f);
    float var  = sq[t] * (1.f/16384.f) - mean*mean;
    float rstd = rsqrtf(var + 1e-5f);
    float s = g[t] * rstd;
    sc[t] = s; sh[t] = bt[t] - mean*s;
  }
  __syncthreads();
  const int c4 = (t & 63) * 4;
  const float s0 = sc[c4], s1 = sc[c4+1], s2 = sc[c4+2], s3 = sc[c4+3];
  const float h0 = sh[c4], h1 = sh[c4+1], h2 = sh[c4+2], h3 = sh[c4+3];
#pragma unroll
  for(int k=0;k<4;k++){
    int m = blockIdx.x*16 + k*4 + (t>>6);
    int b = m >> 12, hh = (m >> 6) & 63, ww = m & 63;
    const float4 v = *(const float4*)(acc + (size_t)m*256 + c4);
    unsigned int lo = (unsigned int)(u16)f2bf(fmaxf(0.f, v.x*s0 + h0))
                    | ((unsigned int)(u16)f2bf(fmaxf(0.f, v.y*s1 + h1)) << 16);
    unsigned int hi = (unsigned int)(u16)f2bf(fmaxf(0.f, v.z*s2 + h2))
                    | ((unsigned int)(u16)f2bf(fmaxf(0.f, v.w*s3 + h3)) << 16);
    uint2 pr; pr.x = lo; pr.y = hi;
    *(uint2*)(o + ((size_t)(b*66 + hh+1)*66 + ww+1)*256 + c4) = pr;
  }
}

// ---------------- BN2 + ReLU + NHWC->NCHW fp32 output ----------------
__global__ void k_bn2_out(const float* __restrict__ acc, const float* __restrict__ sum,
                          const float* __restrict__ sq, const float* __restrict__ g,
                          const float* __restrict__ bt, float* __restrict__ out){
  __shared__ float tile[64][65];
  __shared__ float sc[64], sh[64];
  const int t = threadIdx.x;
  const int b = blockIdx.z, c0 = blockIdx.y*64, hw0 = blockIdx.x*64;
  if(t < 64){
    int c = c0 + t;
    float mean = sum[c] * (1.f/16384.f);
    float var  = sq[c] * (1.f/16384.f) - mean*mean;
    float rstd = rsqrtf(var + 1e-5f);
    float s = g[c] * rstd;
    sc[t] = s; sh[t] = bt[c] - mean*s;
  }
  __syncthreads();
#pragma unroll
  for(int k=0;k<16;k++){
    int idx = t + k*256;
    int wl = idx >> 6, cl = idx & 63;
    float v = acc[(size_t)((b<<12) + hw0 + wl)*256 + c0 + cl];
    tile[wl][cl] = fmaxf(0.f, v*sc[cl] + sh[cl]);
  }
  __syncthreads();
#pragma unroll
  for(int k=0;k<16;k++){
    int idx = t + k*256;
    int cl = idx >> 6, wl = idx & 63;
    out[(size_t)(b*256 + c0 + cl)*4096 + hw0 + wl] = tile[wl][cl];
  }
}

extern "C" void kernel_launch(void* const* d_in, const int* in_sizes, int n_in,
                              void* d_out, int out_size, void* d_ws, size_t ws_size,
                              hipStream_t stream){
  const float* in_v  = (const float*)d_in[0];
  const float* in_i  = (const float*)d_in[1];
  const float* w_off = (const float*)d_in[2];
  const float* b_off = (const float*)d_in[3];
  const float* w_dcn = (const float*)d_in[4];
  const float* g1    = (const float*)d_in[5];
  const float* bt1   = (const float*)d_in[6];
  const float* w2    = (const float*)d_in[7];
  const float* g2    = (const float*)d_in[8];
  const float* bt2   = (const float*)d_in[9];
  float* out = (float*)d_out;
  char* ws = (char*)d_ws;

  float* off_acc  = (float*)(ws + OFF_ACC_B);
  float* out1_acc = (float*)(ws + OUT1_ACC_B);
  float* out2_acc = (float*)(ws + OUT2_ACC_B);
  float* stats    = (float*)(ws + STATS_B);
  float* sum1 = stats,       *sq1 = stats + 256;
  float* sum2 = stats + 512, *sq2 = stats + 768;
  u16* xn_pad    = (u16*)(ws + XN_PAD_B);
  u16* out1n_pad = (u16*)(ws + OUT1N_PAD_B);
  u16* wofft = (u16*)(ws + WOFFT_B);
  u16* wdcnt = (u16*)(ws + WDCNT_B);
  u16* w2t   = (u16*)(ws + W2T_B);
  int*   samp_o = (int*)(ws + SAMP_O_B);
  float* samp_w = (float*)(ws + SAMP_W_B);

  hipMemsetAsync(ws, 0, ZERO_BYTES, stream);
  k_border<<<1040, 256, 0, stream>>>(xn_pad, out1n_pad);
  k_x_to_nhwc<<<dim3(64,8,4), 256, 0, stream>>>(in_v, in_i, xn_pad);
  k_prep_woff<<<576, 256, 0, stream>>>(w_off, wofft);
  k_prep_wdcn<<<4608, 256, 0, stream>>>(w_dcn, wdcnt);
  k_prep_w2<<<2304, 256, 0, stream>>>(w2, w2t);
  k_conv_off<<<dim3(256,6), 256, 0, stream>>>(xn_pad, wofft, off_acc);
  k_sampler<<<576, 256, 0, stream>>>(off_acc, b_off, samp_o, samp_w);
  k_dcn<<<dim3(256,6), 256, 0, stream>>>(xn_pad, wdcnt, samp_o, samp_w, out1_acc);
  k_stats<<<256, 256, 0, stream>>>(out1_acc, sum1, sq1);
  k_bn1<<<1024, 256, 0, stream>>>(out1_acc, sum1, sq1, g1, bt1, out1n_pad);
  k_conv2<<<dim3(256,6), 256, 0, stream>>>(out1n_pad, w2t, out2_acc);
  k_stats<<<256, 256, 0, stream>>>(out2_acc, sum2, sq2);
  k_bn2_out<<<dim3(64,4,4), 256, 0, stream>>>(out2_acc, sum2, sq2, g2, bt2, out);
}

// Round 4
// 393.098 us; speedup vs baseline: 1.0458x; 1.0366x over previous
//
#include <hip/hip_runtime.h>
#include <cstdint>
#include <cstddef>

typedef unsigned short u16;
typedef __attribute__((ext_vector_type(8))) short s16x8;
typedef __attribute__((ext_vector_type(4))) float f32x4;

#define DEV __device__ __forceinline__

DEV float bf2f(short u){
  union { unsigned int i; float f; } v;
  v.i = ((unsigned int)(u16)u) << 16;
  return v.f;
}
DEV short f2bf(float f){
  union { float f; unsigned int i; } v; v.f = f;
  unsigned int u = v.i;
  u += 0x7fffu + ((u >> 16) & 1u);   // RNE
  return (short)(u >> 16);
}
DEV f32x4 f32x4_zero(){
  f32x4 z;
#pragma unroll
  for(int j=0;j<4;j++) z[j]=0.f;
  return z;
}
DEV f32x4 mfma16(s16x8 a, s16x8 b, f32x4 c){
  return __builtin_amdgcn_mfma_f32_16x16x32_bf16(a, b, c, 0, 0, 0);
}
// async global->LDS, 16B/lane; global addr per-lane, LDS dest = uniform base + lane*16B
DEV void cp16(const void* g, void* l){
  __builtin_amdgcn_global_load_lds(
      (const __attribute__((address_space(1))) unsigned int*)g,
      (__attribute__((address_space(3))) unsigned int*)l, 16, 0, 0);
}

// ---------------- problem constants ----------------
// B=4, Cin=512 (concat), H=W=64, P=9 taps, Cout=256, M = B*H*W = 16384
// padded activations: [B][66][66][C] bf16, borders zeroed -> no bounds checks
static constexpr size_t OFF_ACC_B   = 0;                         // float[16384*32]
static constexpr size_t OUT1_ACC_B  = 2097152;                   // float[16384*256]
static constexpr size_t OUT2_ACC_B  = 18874368;                  // float[16384*256]
static constexpr size_t STATS_B     = 35651584;                  // float[1024]
static constexpr size_t ZERO_BYTES  = 35655680;
static constexpr size_t XN_PAD_B    = 35655680;                  // u16[4*66*66*512]
static constexpr size_t OUT1N_PAD_B = 53497856;                  // u16[4*66*66*256]
static constexpr size_t WOFFT_B     = 62418944;                  // u16[9*64*32*8]
static constexpr size_t WDCNT_B     = 62713856;                  // u16[9*64*256*8]
static constexpr size_t W2T_B       = 65073152;                  // u16[9*32*256*8]
static constexpr size_t SAMP_O_B    = 66252800;                  // int[16384*9*4]
static constexpr size_t SAMP_W_B    = 68612096;                  // float[16384*9*4]
static constexpr size_t A_SAMP_B    = 70971392;                  // u16[16384*4608] = 151 MB
// total ~212 MB

// ---------------- zero the padded borders (ws re-poisoned every call) ----------------
__global__ void k_border(u16* __restrict__ xp, u16* __restrict__ op){
  const int cid = blockIdx.x, t = threadIdx.x;       // 1040 border cells
  const int b = cid / 260, rem = cid % 260;
  int y, x;
  if(rem < 132){ y = (rem/66)*65; x = rem%66; }
  else { int r2 = rem-132; x = (r2>>6)*65; y = 1 + (r2&63); }
  const size_t cell = (size_t)(b*66+y)*66 + x;
  ((unsigned int*)(xp + cell*512))[t] = 0;
  if(t < 128) ((unsigned int*)(op + cell*256))[t] = 0;
}

// ---------------- NCHW fp32 (concat) -> padded NHWC bf16 ----------------
__global__ void k_x_to_nhwc(const float* __restrict__ v, const float* __restrict__ vi,
                            u16* __restrict__ xn){
  __shared__ float tile[64][65];
  const int b = blockIdx.z, c0 = blockIdx.y*64, h = blockIdx.x;
  const float* src = (c0 < 256) ? (v  + ((size_t)b*256 + c0)      *4096)
                                : (vi + ((size_t)b*256 + (c0-256))*4096);
  const int t = threadIdx.x;
#pragma unroll
  for(int k=0;k<16;k++){
    int idx = t + k*256;
    int cl = idx >> 6, wl = idx & 63;
    tile[cl][wl] = src[(size_t)cl*4096 + h*64 + wl];
  }
  __syncthreads();
#pragma unroll
  for(int k=0;k<16;k++){
    int idx = t + k*256;
    int wl = idx >> 6, cl = idx & 63;
    xn[((size_t)(b*66 + h+1)*66 + (wl+1))*512 + c0 + cl] = (u16)f2bf(tile[cl][wl]);
  }
}

// ---------------- weight repacks into [tap][kchunk][n][8] bf16 (coalesced B staging) ----------------
__global__ void k_prep_woff(const float* __restrict__ w, u16* __restrict__ wt){
  int i = blockIdx.x*256 + threadIdx.x;        // 9*64*32*8 = 147456
  if(i >= 147456) return;
  int j = i & 7, n = (i>>3) & 31, kcp = i>>8;
  int kc = kcp & 63, tp = kcp >> 6;
  int c = kc*8 + j;
  float val = (n < 27) ? w[(size_t)(n*512 + c)*9 + tp] : 0.f;
  wt[i] = (u16)f2bf(val);
}
__global__ void k_prep_wdcn(const float* __restrict__ w, u16* __restrict__ wt){
  int i = blockIdx.x*256 + threadIdx.x;        // 9*64*256*8 = 1179648
  if(i >= 1179648) return;
  int j = i & 7, n = (i>>3) & 255, kcp = i>>11;
  int kc = kcp & 63, tp = kcp >> 6;
  int c = kc*8 + j;
  wt[i] = (u16)f2bf(w[(size_t)(n*512 + c)*9 + tp]);
}
__global__ void k_prep_w2(const float* __restrict__ w, u16* __restrict__ wt){
  int i = blockIdx.x*256 + threadIdx.x;        // 9*32*256*8 = 589824
  if(i >= 589824) return;
  int j = i & 7, n = (i>>3) & 255, kcp = i>>11;
  int kc = kcp & 31, tp = kcp >> 5;
  int c = kc*8 + j;
  wt[i] = (u16)f2bf(w[(size_t)(n*256 + c)*9 + tp]);
}

// ---------------- offset conv: 512ch -> 27(pad 32); dbuf pipeline, K=32 stages ----------------
// 144 global stages (9 taps x 16); grid (256 m-tiles, 6 k-splits of 24 stages)
__global__ __launch_bounds__(256, 6) void k_conv_off(
    const u16* __restrict__ xn, const u16* __restrict__ wt, float* __restrict__ offa){
  __shared__ short A[2][4][64][8];   // [buf][chunk][row][8]  8KB
  __shared__ short B[2][4][32][8];   // 4KB
  const int tid = threadIdx.x;
  const int lane = tid & 63, wid = tid >> 6;
  const int quad = lane >> 4, ln = lane & 15;
  const int m0 = blockIdx.x * 64;
  const int b = m0 >> 12, h = (m0 >> 6) & 63;
  const int gst0 = blockIdx.y * 24;
  const int m_base = wid * 16;
  f32x4 acc0 = f32x4_zero(), acc1 = f32x4_zero();

  {
    const int tp = gst0 >> 4, s = gst0 & 15;
    const int ty = tp/3, tx = tp - ty*3;
    cp16(xn + ((size_t)(b*66 + h+ty)*66 + lane + tx)*512 + s*32 + wid*8, &A[0][wid][0][0]);
    if(wid < 2)
      cp16(wt + ((size_t)tp*64 + s*4)*256 + wid*512 + lane*8, (short*)&B[0][0][0][0] + wid*512);
  }
  __syncthreads();

  int buf = 0;
  for(int it=0; it<24; it++){
    const int nb = buf ^ 1;
    if(it < 23){
      const int gn = gst0 + it + 1;
      const int tp = gn >> 4, s = gn & 15;
      const int ty = tp/3, tx = tp - ty*3;
      cp16(xn + ((size_t)(b*66 + h+ty)*66 + lane + tx)*512 + s*32 + wid*8, &A[nb][wid][0][0]);
      if(wid < 2)
        cp16(wt + ((size_t)tp*64 + s*4)*256 + wid*512 + lane*8, (short*)&B[nb][0][0][0] + wid*512);
    }
    const s16x8* Ap = (const s16x8*)&A[buf][0][0][0];
    const s16x8* Bp = (const s16x8*)&B[buf][0][0][0];
    s16x8 a  = Ap[quad*64 + m_base + ln];
    s16x8 b0 = Bp[quad*32 + ln];
    s16x8 b1 = Bp[quad*32 + 16 + ln];
    acc0 = mfma16(a, b0, acc0);
    acc1 = mfma16(a, b1, acc1);
    __syncthreads();
    buf = nb;
  }
#pragma unroll
  for(int nf=0;nf<2;nf++){
    const f32x4 v = nf ? acc1 : acc0;
    const int col = nf*16 + ln;
#pragma unroll
    for(int i=0;i<4;i++){
      const int row = m_base + quad*4 + i;
      unsafeAtomicAdd(offa + (size_t)(m0+row)*32 + col, v[i]);
    }
  }
}

// ---------------- sampler: precompute bilinear taps (padded offsets + weights) ----------------
__global__ void k_sampler(const float* __restrict__ offa, const float* __restrict__ boff,
                          int* __restrict__ so, float* __restrict__ sw){
  const int idx = blockIdx.x*256 + threadIdx.x;
  if(idx >= 16384*9) return;
  const int m = idx / 9, tp = idx - m*9;
  const int b = m >> 12, h = (m >> 6) & 63, w = m & 63;
  const float* orow = offa + (size_t)m*32;
  float dy = orow[2*tp]   + boff[2*tp];
  float dx = orow[2*tp+1] + boff[2*tp+1];
  float mz = orow[18+tp]  + boff[18+tp];
  float mk = 1.f / (1.f + expf(-mz));
  float ypos = (float)(h - 1 + tp/3) + dy;
  float xpos = (float)(w - 1 + tp%3) + dx;
  float y0f = floorf(ypos), x0f = floorf(xpos);
  float ly = ypos - y0f, lx = xpos - x0f;
  int y0 = (int)y0f, x0 = (int)x0f;
#pragma unroll
  for(int k=0;k<4;k++){
    int ddy = k >> 1, ddx = k & 1;
    int yi = y0 + ddy, xi = x0 + ddx;
    bool vv = (yi >= 0) & (yi < 64) & (xi >= 0) & (xi < 64);
    float wk = (ddy ? ly : 1.f-ly) * (ddx ? lx : 1.f-lx) * mk;
    if(!vv) wk = 0.f;
    int yc = yi < 0 ? 0 : (yi > 63 ? 63 : yi);
    int xc = xi < 0 ? 0 : (xi > 63 ? 63 : xi);
    so[(size_t)idx*4 + k] = ((b*66 + yc+1)*66 + xc+1) << 9;   // *512 (padded)
    sw[(size_t)idx*4 + k] = wk;
  }
}

// ---------------- sample A: materialize [16384][9*512] bf16 (barrier-free, latency-tolerant) ----------------
// XCD-swizzled: same-XCD blocks cover contiguous pixel ranges -> gather hits XCD-local L2
__global__ __launch_bounds__(256) void k_sample_a(
    const u16* __restrict__ xn, const int* __restrict__ so, const float* __restrict__ sw,
    u16* __restrict__ as){
  const int blk = blockIdx.x;                      // 256 blocks
  const int pb = ((blk & 7) << 5) | (blk >> 3);    // XCD-contiguous pixel-block
  const int m = pb*64 + (threadIdx.x >> 2);
  const int q = threadIdx.x & 3;                   // 8-ch sub-slot within 32-ch chunk
  for(int tp=0; tp<9; tp++){
    const int4   po = *(const int4*)  (so + ((size_t)m*9 + tp)*4);
    const float4 pw = *(const float4*)(sw + ((size_t)m*9 + tp)*4);
    const u16* x0 = xn + po.x + q*8;
    const u16* x1 = xn + po.y + q*8;
    const u16* x2 = xn + po.z + q*8;
    const u16* x3 = xn + po.w + q*8;
    u16* dst = as + (size_t)m*4608 + tp*512 + q*8;
#pragma unroll 4
    for(int u=0; u<16; u++){
      const int c0 = u*32;                         // 4 lanes x 8ch = 32-ch chunk
      s16x8 g0 = *(const s16x8*)(x0 + c0);
      s16x8 g1 = *(const s16x8*)(x1 + c0);
      s16x8 g2 = *(const s16x8*)(x2 + c0);
      s16x8 g3 = *(const s16x8*)(x3 + c0);
      s16x8 pk;
#pragma unroll
      for(int j=0;j<8;j++){
        float f = pw.x * bf2f(g0[j]);
        f = fmaf(pw.y, bf2f(g1[j]), f);
        f = fmaf(pw.z, bf2f(g2[j]), f);
        f = fmaf(pw.w, bf2f(g3[j]), f);
        pk[j] = f2bf(f);
      }
      *(s16x8*)(dst + c0) = pk;
    }
  }
}

// ---------------- DCN dense GEMM: M=16384 K=4608 N=256, all-cp16 dbuf, K=32 stages ----------------
// 144 global stages; grid (256 m-tiles, 3 k-splits of 48 stages)
__global__ __launch_bounds__(256, 4) void k_dcn_gemm(
    const u16* __restrict__ as, const u16* __restrict__ wt, float* __restrict__ outa){
  __shared__ short A[2][4][64][8];    // 8KB
  __shared__ short B[2][4][256][8];   // 32KB
  const int tid = threadIdx.x;
  const int lane = tid & 63, wid = tid >> 6;
  const int quad = lane >> 4, ln = lane & 15;
  const int m0 = blockIdx.x * 64;
  const int gst0 = blockIdx.y * 48;
  const int m_base = (wid >> 1)*32, n_base = (wid & 1)*128;
  f32x4 acc[2][8];
#pragma unroll
  for(int mf=0;mf<2;mf++)
#pragma unroll
    for(int nf=0;nf<8;nf++) acc[mf][nf] = f32x4_zero();

  const u16* arow = as + (size_t)(m0 + lane)*4608;

  {
    const int tp = gst0 >> 4, s = gst0 & 15;
    cp16(arow + gst0*32 + wid*8, &A[0][wid][0][0]);
    const u16* bs = wt + ((size_t)tp*64 + s*4)*2048 + (wid*4)*512 + lane*8;
    short* bd = (short*)&B[0][0][0][0] + (wid*4)*512;
#pragma unroll
    for(int i=0;i<4;i++) cp16(bs + i*512, bd + i*512);
  }
  __syncthreads();

  int buf = 0;
  for(int it=0; it<48; it++){
    const int nb = buf ^ 1;
    if(it < 47){
      const int gn = gst0 + it + 1;
      const int tp = gn >> 4, s = gn & 15;
      cp16(arow + gn*32 + wid*8, &A[nb][wid][0][0]);
      const u16* bs = wt + ((size_t)tp*64 + s*4)*2048 + (wid*4)*512 + lane*8;
      short* bd = (short*)&B[nb][0][0][0] + (wid*4)*512;
#pragma unroll
      for(int i=0;i<4;i++) cp16(bs + i*512, bd + i*512);
    }
    const s16x8* Ap = (const s16x8*)&A[buf][0][0][0];
    const s16x8* Bp = (const s16x8*)&B[buf][0][0][0];
    s16x8 a0 = Ap[quad*64 + m_base + ln];
    s16x8 a1 = Ap[quad*64 + m_base + 16 + ln];
#pragma unroll
    for(int nf=0;nf<8;nf++){
      s16x8 bf = Bp[quad*256 + n_base + nf*16 + ln];
      acc[0][nf] = mfma16(a0, bf, acc[0][nf]);
      acc[1][nf] = mfma16(a1, bf, acc[1][nf]);
    }
    __syncthreads();
    buf = nb;
  }
#pragma unroll
  for(int mf=0;mf<2;mf++)
#pragma unroll
    for(int nf=0;nf<8;nf++){
      const int col = n_base + nf*16 + ln;
#pragma unroll
      for(int i=0;i<4;i++){
        const int row = m_base + mf*16 + quad*4 + i;
        unsafeAtomicAdd(outa + (size_t)(m0+row)*256 + col, acc[mf][nf][i]);
      }
    }
}

// ---------------- conv2: 256 -> 256, dbuf all-cp16 pipeline, K=32 stages ----------------
// 72 global stages (9 taps x 8); grid (256 m-tiles, 3 k-splits of 24 stages)
__global__ __launch_bounds__(256, 4) void k_conv2(
    const u16* __restrict__ a_in, const u16* __restrict__ wt, float* __restrict__ outa){
  __shared__ short A[2][4][64][8];    // 8KB
  __shared__ short B[2][4][256][8];   // 32KB
  const int tid = threadIdx.x;
  const int lane = tid & 63, wid = tid >> 6;
  const int quad = lane >> 4, ln = lane & 15;
  const int m0 = blockIdx.x * 64;
  const int b = m0 >> 12, h = (m0 >> 6) & 63;
  const int gst0 = blockIdx.y * 24;
  const int m_base = (wid >> 1)*32, n_base = (wid & 1)*128;
  f32x4 acc[2][8];
#pragma unroll
  for(int mf=0;mf<2;mf++)
#pragma unroll
    for(int nf=0;nf<8;nf++) acc[mf][nf] = f32x4_zero();

  {
    const int tp = gst0 >> 3, s = gst0 & 7;
    const int ty = tp/3, tx = tp - ty*3;
    cp16(a_in + ((size_t)(b*66 + h+ty)*66 + lane + tx)*256 + s*32 + wid*8, &A[0][wid][0][0]);
    const u16* bs = wt + ((size_t)tp*32 + s*4)*2048 + (wid*4)*512 + lane*8;
    short* bd = (short*)&B[0][0][0][0] + (wid*4)*512;
#pragma unroll
    for(int i=0;i<4;i++) cp16(bs + i*512, bd + i*512);
  }
  __syncthreads();

  int buf = 0;
  for(int it=0; it<24; it++){
    const int nb = buf ^ 1;
    if(it < 23){
      const int gn = gst0 + it + 1;
      const int tp = gn >> 3, s = gn & 7;
      const int ty = tp/3, tx = tp - ty*3;
      cp16(a_in + ((size_t)(b*66 + h+ty)*66 + lane + tx)*256 + s*32 + wid*8, &A[nb][wid][0][0]);
      const u16* bs = wt + ((size_t)tp*32 + s*4)*2048 + (wid*4)*512 + lane*8;
      short* bd = (short*)&B[nb][0][0][0] + (wid*4)*512;
#pragma unroll
      for(int i=0;i<4;i++) cp16(bs + i*512, bd + i*512);
    }
    const s16x8* Ap = (const s16x8*)&A[buf][0][0][0];
    const s16x8* Bp = (const s16x8*)&B[buf][0][0][0];
    s16x8 a0 = Ap[quad*64 + m_base + ln];
    s16x8 a1 = Ap[quad*64 + m_base + 16 + ln];
#pragma unroll
    for(int nf=0;nf<8;nf++){
      s16x8 bf = Bp[quad*256 + n_base + nf*16 + ln];
      acc[0][nf] = mfma16(a0, bf, acc[0][nf]);
      acc[1][nf] = mfma16(a1, bf, acc[1][nf]);
    }
    __syncthreads();
    buf = nb;
  }
#pragma unroll
  for(int mf=0;mf<2;mf++)
#pragma unroll
    for(int nf=0;nf<8;nf++){
      const int col = n_base + nf*16 + ln;
#pragma unroll
      for(int i=0;i<4;i++){
        const int row = m_base + mf*16 + quad*4 + i;
        unsafeAtomicAdd(outa + (size_t)(m0+row)*256 + col, acc[mf][nf][i]);
      }
    }
}

// ---------------- BN stats: per-channel sum/sumsq over M=16384 ----------------
__global__ void k_stats(const float* __restrict__ acc, float* __restrict__ sum,
                        float* __restrict__ sq){
  const int m0 = blockIdx.x*64;
  const int c = threadIdx.x;
  float s = 0.f, q = 0.f;
  for(int i=0;i<64;i++){
    float v = acc[(size_t)(m0+i)*256 + c];
    s += v; q += v*v;
  }
  unsafeAtomicAdd(sum + c, s);
  unsafeAtomicAdd(sq + c, q);
}

// ---------------- BN1 + ReLU -> padded bf16 NHWC ----------------
__global__ void k_bn1(const float* __restrict__ acc, const float* __restrict__ sum,
                      const float* __restrict__ sq, const float* __restrict__ g,
                      const float* __restrict__ bt, u16* __restrict__ o){
  __shared__ float sc[256], sh[256];
  const int t = threadIdx.x;
  {
    float mean = sum[t] * (1.f/16384.f);
    float var  = sq[t] * (1.f/16384.f) - mean*mean;
    float rstd = rsqrtf(var + 1e-5f);
    float s = g[t] * rstd;
    sc[t] = s; sh[t] = bt[t] - mean*s;
  }
  __syncthreads();
  const int c4 = (t & 63) * 4;
  const float s0 = sc[c4], s1 = sc[c4+1], s2 = sc[c4+2], s3 = sc[c4+3];
  const float h0 = sh[c4], h1 = sh[c4+1], h2 = sh[c4+2], h3 = sh[c4+3];
#pragma unroll
  for(int k=0;k<4;k++){
    int m = blockIdx.x*16 + k*4 + (t>>6);
    int b = m >> 12, hh = (m >> 6) & 63, ww = m & 63;
    const float4 v = *(const float4*)(acc + (size_t)m*256 + c4);
    unsigned int lo = (unsigned int)(u16)f2bf(fmaxf(0.f, v.x*s0 + h0))
                    | ((unsigned int)(u16)f2bf(fmaxf(0.f, v.y*s1 + h1)) << 16);
    unsigned int hi = (unsigned int)(u16)f2bf(fmaxf(0.f, v.z*s2 + h2))
                    | ((unsigned int)(u16)f2bf(fmaxf(0.f, v.w*s3 + h3)) << 16);
    uint2 pr; pr.x = lo; pr.y = hi;
    *(uint2*)(o + ((size_t)(b*66 + hh+1)*66 + ww+1)*256 + c4) = pr;
  }
}

// ---------------- BN2 + ReLU + NHWC->NCHW fp32 output ----------------
__global__ void k_bn2_out(const float* __restrict__ acc, const float* __restrict__ sum,
                          const float* __restrict__ sq, const float* __restrict__ g,
                          const float* __restrict__ bt, float* __restrict__ out){
  __shared__ float tile[64][65];
  __shared__ float sc[64], sh[64];
  const int t = threadIdx.x;
  const int b = blockIdx.z, c0 = blockIdx.y*64, hw0 = blockIdx.x*64;
  if(t < 64){
    int c = c0 + t;
    float mean = sum[c] * (1.f/16384.f);
    float var  = sq[c] * (1.f/16384.f) - mean*mean;
    float rstd = rsqrtf(var + 1e-5f);
    float s = g[c] * rstd;
    sc[t] = s; sh[t] = bt[c] - mean*s;
  }
  __syncthreads();
#pragma unroll
  for(int k=0;k<16;k++){
    int idx = t + k*256;
    int wl = idx >> 6, cl = idx & 63;
    float v = acc[(size_t)((b<<12) + hw0 + wl)*256 + c0 + cl];
    tile[wl][cl] = fmaxf(0.f, v*sc[cl] + sh[cl]);
  }
  __syncthreads();
#pragma unroll
  for(int k=0;k<16;k++){
    int idx = t + k*256;
    int cl = idx >> 6, wl = idx & 63;
    out[(size_t)(b*256 + c0 + cl)*4096 + hw0 + wl] = tile[wl][cl];
  }
}

extern "C" void kernel_launch(void* const* d_in, const int* in_sizes, int n_in,
                              void* d_out, int out_size, void* d_ws, size_t ws_size,
                              hipStream_t stream){
  const float* in_v  = (const float*)d_in[0];
  const float* in_i  = (const float*)d_in[1];
  const float* w_off = (const float*)d_in[2];
  const float* b_off = (const float*)d_in[3];
  const float* w_dcn = (const float*)d_in[4];
  const float* g1    = (const float*)d_in[5];
  const float* bt1   = (const float*)d_in[6];
  const float* w2    = (const float*)d_in[7];
  const float* g2    = (const float*)d_in[8];
  const float* bt2   = (const float*)d_in[9];
  float* out = (float*)d_out;
  char* ws = (char*)d_ws;

  float* off_acc  = (float*)(ws + OFF_ACC_B);
  float* out1_acc = (float*)(ws + OUT1_ACC_B);
  float* out2_acc = (float*)(ws + OUT2_ACC_B);
  float* stats    = (float*)(ws + STATS_B);
  float* sum1 = stats,       *sq1 = stats + 256;
  float* sum2 = stats + 512, *sq2 = stats + 768;
  u16* xn_pad    = (u16*)(ws + XN_PAD_B);
  u16* out1n_pad = (u16*)(ws + OUT1N_PAD_B);
  u16* wofft = (u16*)(ws + WOFFT_B);
  u16* wdcnt = (u16*)(ws + WDCNT_B);
  u16* w2t   = (u16*)(ws + W2T_B);
  int*   samp_o = (int*)(ws + SAMP_O_B);
  float* samp_w = (float*)(ws + SAMP_W_B);
  u16* a_samp = (u16*)(ws + A_SAMP_B);

  hipMemsetAsync(ws, 0, ZERO_BYTES, stream);
  k_border<<<1040, 256, 0, stream>>>(xn_pad, out1n_pad);
  k_x_to_nhwc<<<dim3(64,8,4), 256, 0, stream>>>(in_v, in_i, xn_pad);
  k_prep_woff<<<576, 256, 0, stream>>>(w_off, wofft);
  k_prep_wdcn<<<4608, 256, 0, stream>>>(w_dcn, wdcnt);
  k_prep_w2<<<2304, 256, 0, stream>>>(w2, w2t);
  k_conv_off<<<dim3(256,6), 256, 0, stream>>>(xn_pad, wofft, off_acc);
  k_sampler<<<576, 256, 0, stream>>>(off_acc, b_off, samp_o, samp_w);
  k_sample_a<<<256, 256, 0, stream>>>(xn_pad, samp_o, samp_w, a_samp);
  k_dcn_gemm<<<dim3(256,3), 256, 0, stream>>>(a_samp, wdcnt, out1_acc);
  k_stats<<<256, 256, 0, stream>>>(out1_acc, sum1, sq1);
  k_bn1<<<1024, 256, 0, stream>>>(out1_acc, sum1, sq1, g1, bt1, out1n_pad);
  k_conv2<<<dim3(256,3), 256, 0, stream>>>(out1n_pad, w2t, out2_acc);
  k_stats<<<256, 256, 0, stream>>>(out2_acc, sum2, sq2);
  k_bn2_out<<<dim3(64,4,4), 256, 0, stream>>>(out2_acc, sum2, sq2, g2, bt2, out);
}

// Round 5
// 382.014 us; speedup vs baseline: 1.0761x; 1.0290x over previous
//
#include <hip/hip_runtime.h>
#include <cstdint>
#include <cstddef>

typedef unsigned short u16;
typedef __attribute__((ext_vector_type(8))) short s16x8;
typedef __attribute__((ext_vector_type(4))) float f32x4;

#define DEV __device__ __forceinline__

DEV float bf2f(short u){
  union { unsigned int i; float f; } v;
  v.i = ((unsigned int)(u16)u) << 16;
  return v.f;
}
DEV short f2bf(float f){
  union { float f; unsigned int i; } v; v.f = f;
  unsigned int u = v.i;
  u += 0x7fffu + ((u >> 16) & 1u);   // RNE
  return (short)(u >> 16);
}
DEV f32x4 f32x4_zero(){
  f32x4 z;
#pragma unroll
  for(int j=0;j<4;j++) z[j]=0.f;
  return z;
}
DEV f32x4 mfma16(s16x8 a, s16x8 b, f32x4 c){
  return __builtin_amdgcn_mfma_f32_16x16x32_bf16(a, b, c, 0, 0, 0);
}
// async global->LDS, 16B/lane; global addr per-lane, LDS dest = uniform base + lane*16B
DEV void cp16(const void* g, void* l){
  __builtin_amdgcn_global_load_lds(
      (const __attribute__((address_space(1))) unsigned int*)g,
      (__attribute__((address_space(3))) unsigned int*)l, 16, 0, 0);
}

// ---------------- problem constants ----------------
// B=4, Cin=512 (concat), H=W=64, P=9 taps, Cout=256, M = B*H*W = 16384
static constexpr size_t OFF_ACC_B   = 0;                         // float[16384*32]
static constexpr size_t OUT1_ACC_B  = 2097152;                   // float[16384*256]
static constexpr size_t OUT2_ACC_B  = 18874368;                  // float[16384*256]
static constexpr size_t STATS_B     = 35651584;                  // float[1024]
static constexpr size_t ZERO_BYTES  = 35655680;
static constexpr size_t XN_PAD_B    = 35655680;                  // u16[4*66*66*512]
static constexpr size_t OUT1N_PAD_B = 53497856;                  // u16[4*66*66*256]
static constexpr size_t WOFFT_B     = 62418944;                  // u16[9*64*32*8]
static constexpr size_t WDCNT_B     = 62713856;                  // u16[9*64*256*8]
static constexpr size_t W2T_B       = 65073152;                  // u16[9*32*256*8]
static constexpr size_t SAMP_O_B    = 66252800;                  // int[16384*9*4]
static constexpr size_t SAMP_W_B    = 68612096;                  // float[16384*9*4]
static constexpr size_t A_SAMP_B    = 70971392;                  // u16[16384*4608] = 151 MB

// ---------------- zero the padded borders ----------------
__global__ void k_border(u16* __restrict__ xp, u16* __restrict__ op){
  const int cid = blockIdx.x, t = threadIdx.x;       // 1040 border cells
  const int b = cid / 260, rem = cid % 260;
  int y, x;
  if(rem < 132){ y = (rem/66)*65; x = rem%66; }
  else { int r2 = rem-132; x = (r2>>6)*65; y = 1 + (r2&63); }
  const size_t cell = (size_t)(b*66+y)*66 + x;
  ((unsigned int*)(xp + cell*512))[t] = 0;
  if(t < 128) ((unsigned int*)(op + cell*256))[t] = 0;
}

// ---------------- NCHW fp32 (concat) -> padded NHWC bf16 ----------------
__global__ void k_x_to_nhwc(const float* __restrict__ v, const float* __restrict__ vi,
                            u16* __restrict__ xn){
  __shared__ float tile[64][65];
  const int b = blockIdx.z, c0 = blockIdx.y*64, h = blockIdx.x;
  const float* src = (c0 < 256) ? (v  + ((size_t)b*256 + c0)      *4096)
                                : (vi + ((size_t)b*256 + (c0-256))*4096);
  const int t = threadIdx.x;
#pragma unroll
  for(int k=0;k<16;k++){
    int idx = t + k*256;
    int cl = idx >> 6, wl = idx & 63;
    tile[cl][wl] = src[(size_t)cl*4096 + h*64 + wl];
  }
  __syncthreads();
#pragma unroll
  for(int k=0;k<16;k++){
    int idx = t + k*256;
    int wl = idx >> 6, cl = idx & 63;
    xn[((size_t)(b*66 + h+1)*66 + (wl+1))*512 + c0 + cl] = (u16)f2bf(tile[cl][wl]);
  }
}

// ---------------- weight repacks into [kcp][n][8] bf16 (kcp = k/8, n fastest-coalesced) ----------------
__global__ void k_prep_woff(const float* __restrict__ w, u16* __restrict__ wt){
  int i = blockIdx.x*256 + threadIdx.x;        // 9*64*32*8 = 147456
  if(i >= 147456) return;
  int j = i & 7, n = (i>>3) & 31, kcp = i>>8;
  int kc = kcp & 63, tp = kcp >> 6;
  int c = kc*8 + j;
  float val = (n < 27) ? w[(size_t)(n*512 + c)*9 + tp] : 0.f;
  wt[i] = (u16)f2bf(val);
}
__global__ void k_prep_wdcn(const float* __restrict__ w, u16* __restrict__ wt){
  int i = blockIdx.x*256 + threadIdx.x;        // 9*64*256*8 = 1179648
  if(i >= 1179648) return;
  int j = i & 7, n = (i>>3) & 255, kcp = i>>11;
  int kc = kcp & 63, tp = kcp >> 6;
  int c = kc*8 + j;
  wt[i] = (u16)f2bf(w[(size_t)(n*512 + c)*9 + tp]);
}
__global__ void k_prep_w2(const float* __restrict__ w, u16* __restrict__ wt){
  int i = blockIdx.x*256 + threadIdx.x;        // 9*32*256*8 = 589824
  if(i >= 589824) return;
  int j = i & 7, n = (i>>3) & 255, kcp = i>>11;
  int kc = kcp & 31, tp = kcp >> 5;
  int c = kc*8 + j;
  wt[i] = (u16)f2bf(w[(size_t)(n*256 + c)*9 + tp]);
}

// ---------------- offset conv: 512ch -> 27(pad 32); dbuf pipeline, K=32 stages ----------------
__global__ __launch_bounds__(256, 6) void k_conv_off(
    const u16* __restrict__ xn, const u16* __restrict__ wt, float* __restrict__ offa){
  __shared__ short A[2][4][64][8];
  __shared__ short B[2][4][32][8];
  const int tid = threadIdx.x;
  const int lane = tid & 63, wid = tid >> 6;
  const int quad = lane >> 4, ln = lane & 15;
  const int m0 = blockIdx.x * 64;
  const int b = m0 >> 12, h = (m0 >> 6) & 63;
  const int gst0 = blockIdx.y * 24;
  const int m_base = wid * 16;
  f32x4 acc0 = f32x4_zero(), acc1 = f32x4_zero();

  {
    const int tp = gst0 >> 4, s = gst0 & 15;
    const int ty = tp/3, tx = tp - ty*3;
    cp16(xn + ((size_t)(b*66 + h+ty)*66 + lane + tx)*512 + s*32 + wid*8, &A[0][wid][0][0]);
    if(wid < 2)
      cp16(wt + ((size_t)tp*64 + s*4)*256 + wid*512 + lane*8, (short*)&B[0][0][0][0] + wid*512);
  }
  __syncthreads();

  int buf = 0;
  for(int it=0; it<24; it++){
    const int nb = buf ^ 1;
    if(it < 23){
      const int gn = gst0 + it + 1;
      const int tp = gn >> 4, s = gn & 15;
      const int ty = tp/3, tx = tp - ty*3;
      cp16(xn + ((size_t)(b*66 + h+ty)*66 + lane + tx)*512 + s*32 + wid*8, &A[nb][wid][0][0]);
      if(wid < 2)
        cp16(wt + ((size_t)tp*64 + s*4)*256 + wid*512 + lane*8, (short*)&B[nb][0][0][0] + wid*512);
    }
    const s16x8* Ap = (const s16x8*)&A[buf][0][0][0];
    const s16x8* Bp = (const s16x8*)&B[buf][0][0][0];
    s16x8 a  = Ap[quad*64 + m_base + ln];
    s16x8 b0 = Bp[quad*32 + ln];
    s16x8 b1 = Bp[quad*32 + 16 + ln];
    acc0 = mfma16(a, b0, acc0);
    acc1 = mfma16(a, b1, acc1);
    __syncthreads();
    buf = nb;
  }
#pragma unroll
  for(int nf=0;nf<2;nf++){
    const f32x4 v = nf ? acc1 : acc0;
    const int col = nf*16 + ln;
#pragma unroll
    for(int i=0;i<4;i++){
      const int row = m_base + quad*4 + i;
      unsafeAtomicAdd(offa + (size_t)(m0+row)*32 + col, v[i]);
    }
  }
}

// ---------------- sampler: precompute bilinear taps ----------------
__global__ void k_sampler(const float* __restrict__ offa, const float* __restrict__ boff,
                          int* __restrict__ so, float* __restrict__ sw){
  const int idx = blockIdx.x*256 + threadIdx.x;
  if(idx >= 16384*9) return;
  const int m = idx / 9, tp = idx - m*9;
  const int b = m >> 12, h = (m >> 6) & 63, w = m & 63;
  const float* orow = offa + (size_t)m*32;
  float dy = orow[2*tp]   + boff[2*tp];
  float dx = orow[2*tp+1] + boff[2*tp+1];
  float mz = orow[18+tp]  + boff[18+tp];
  float mk = 1.f / (1.f + expf(-mz));
  float ypos = (float)(h - 1 + tp/3) + dy;
  float xpos = (float)(w - 1 + tp%3) + dx;
  float y0f = floorf(ypos), x0f = floorf(xpos);
  float ly = ypos - y0f, lx = xpos - x0f;
  int y0 = (int)y0f, x0 = (int)x0f;
#pragma unroll
  for(int k=0;k<4;k++){
    int ddy = k >> 1, ddx = k & 1;
    int yi = y0 + ddy, xi = x0 + ddx;
    bool vv = (yi >= 0) & (yi < 64) & (xi >= 0) & (xi < 64);
    float wk = (ddy ? ly : 1.f-ly) * (ddx ? lx : 1.f-lx) * mk;
    if(!vv) wk = 0.f;
    int yc = yi < 0 ? 0 : (yi > 63 ? 63 : yi);
    int xc = xi < 0 ? 0 : (xi > 63 ? 63 : xi);
    so[(size_t)idx*4 + k] = ((b*66 + yc+1)*66 + xc+1) << 9;   // *512 (padded)
    sw[(size_t)idx*4 + k] = wk;
  }
}

// ---------------- sample A: materialize [16384][9*512] bf16; 2304 blocks (pixel-block x tap) ----------------
// XCD-major: blk&7 = XCD slot; each XCD covers contiguous 32 pixel-blocks (2 MB x-rows in its L2)
__global__ __launch_bounds__(256) void k_sample_a(
    const u16* __restrict__ xn, const int* __restrict__ so, const float* __restrict__ sw,
    u16* __restrict__ as){
  const int blk = blockIdx.x;                  // 2304 = 8 * 32 * 9
  const int x = blk & 7, g = blk >> 3;
  const int tp = g >> 5, pbi = g & 31;
  const int pb = x*32 + pbi;
  const int m = pb*64 + (threadIdx.x >> 2);
  const int q = threadIdx.x & 3;               // 8-ch sub-slot within 32-ch chunk
  const int4   po = *(const int4*)  (so + ((size_t)m*9 + tp)*4);
  const float4 pw = *(const float4*)(sw + ((size_t)m*9 + tp)*4);
  const u16* x0 = xn + po.x + q*8;
  const u16* x1 = xn + po.y + q*8;
  const u16* x2 = xn + po.z + q*8;
  const u16* x3 = xn + po.w + q*8;
  u16* dst = as + (size_t)m*4608 + tp*512 + q*8;
#pragma unroll 4
  for(int u=0; u<16; u++){
    const int c0 = u*32;
    s16x8 g0 = *(const s16x8*)(x0 + c0);
    s16x8 g1 = *(const s16x8*)(x1 + c0);
    s16x8 g2 = *(const s16x8*)(x2 + c0);
    s16x8 g3 = *(const s16x8*)(x3 + c0);
    s16x8 pk;
#pragma unroll
    for(int j=0;j<8;j++){
      float f = pw.x * bf2f(g0[j]);
      f = fmaf(pw.y, bf2f(g1[j]), f);
      f = fmaf(pw.z, bf2f(g2[j]), f);
      f = fmaf(pw.w, bf2f(g3[j]), f);
      pk[j] = f2bf(f);
    }
    *(s16x8*)(dst + c0) = pk;
  }
}

// ---------------- DCN dense GEMM: m97 structure. 128x128 tile, BK=64, single-buf, 2 barriers ----------------
// grid (128 m-tiles, 2 n-tiles, 3 k-splits of 24 BK-iters); 4 waves, wave = 64x64 (4x4 frags)
__global__ __launch_bounds__(256, 3) void k_dcn_gemm(
    const u16* __restrict__ as, const u16* __restrict__ wt, float* __restrict__ outa){
  __shared__ short A[8][128][8];   // 16KB [kc][row][8]
  __shared__ short B[8][128][8];   // 16KB [kc][n][8]
  const int tid = threadIdx.x;
  const int lane = tid & 63, wid = tid >> 6;
  const int quad = lane >> 4, ln = lane & 15;
  const int m0 = blockIdx.x * 128, n0 = blockIdx.y * 128;
  const int it0 = blockIdx.z * 24;
  const int m_w = (wid >> 1)*64, n_w = (wid & 1)*64;
  const s16x8* Ap = (const s16x8*)A;
  const s16x8* Bp = (const s16x8*)B;
  f32x4 acc[4][4];
#pragma unroll
  for(int mf=0;mf<4;mf++)
#pragma unroll
    for(int nf=0;nf<4;nf++) acc[mf][nf] = f32x4_zero();

  const u16* arow0 = as + (size_t)(m0 + lane)*4608;        // rh=0
  const u16* arow1 = as + (size_t)(m0 + 64 + lane)*4608;   // rh=1

  for(int it=0; it<24; it++){
    const int k0 = (it0 + it)*64;
#pragma unroll
    for(int i=0;i<4;i++){
      const int tt = wid*4 + i, kc = tt >> 1, rh = tt & 1;
      cp16((rh ? arow1 : arow0) + k0 + kc*8, &A[kc][rh*64][0]);
    }
#pragma unroll
    for(int i=0;i<4;i++){
      const int tt = wid*4 + i, kc = tt >> 1, nh = tt & 1;
      cp16(wt + ((size_t)((k0>>3) + kc)*256 + n0 + nh*64 + lane)*8, &B[kc][nh*64][0]);
    }
    __syncthreads();
#pragma unroll
    for(int ks=0; ks<2; ks++){
      s16x8 af[4], bf[4];
#pragma unroll
      for(int mf=0;mf<4;mf++) af[mf] = Ap[(ks*4+quad)*128 + m_w + mf*16 + ln];
#pragma unroll
      for(int nf=0;nf<4;nf++) bf[nf] = Bp[(ks*4+quad)*128 + n_w + nf*16 + ln];
#pragma unroll
      for(int mf=0;mf<4;mf++)
#pragma unroll
        for(int nf=0;nf<4;nf++)
          acc[mf][nf] = mfma16(af[mf], bf[nf], acc[mf][nf]);
    }
    __syncthreads();
  }
#pragma unroll
  for(int mf=0;mf<4;mf++)
#pragma unroll
    for(int nf=0;nf<4;nf++){
      const int col = n0 + n_w + nf*16 + ln;
#pragma unroll
      for(int i=0;i<4;i++){
        const int row = m0 + m_w + mf*16 + quad*4 + i;
        unsafeAtomicAdd(outa + (size_t)row*256 + col, acc[mf][nf][i]);
      }
    }
}

// ---------------- conv2: m97 structure on padded out1n. K=2304, BK=64 ----------------
// grid (128 m-tiles, 2 n-tiles, 3 k-splits of 12 BK-iters)
__global__ __launch_bounds__(256, 3) void k_conv2(
    const u16* __restrict__ a_in, const u16* __restrict__ wt, float* __restrict__ outa){
  __shared__ short A[8][128][8];   // 16KB
  __shared__ short B[8][128][8];   // 16KB
  const int tid = threadIdx.x;
  const int lane = tid & 63, wid = tid >> 6;
  const int quad = lane >> 4, ln = lane & 15;
  const int m0 = blockIdx.x * 128, n0 = blockIdx.y * 128;
  const int it0 = blockIdx.z * 12;
  const int m_w = (wid >> 1)*64, n_w = (wid & 1)*64;
  const s16x8* Ap = (const s16x8*)A;
  const s16x8* Bp = (const s16x8*)B;
  f32x4 acc[4][4];
#pragma unroll
  for(int mf=0;mf<4;mf++)
#pragma unroll
    for(int nf=0;nf<4;nf++) acc[mf][nf] = f32x4_zero();

  // per-lane pixel cells for rh=0/1 (constant over iters)
  int cell[2];
#pragma unroll
  for(int rh=0; rh<2; rh++){
    const int m = m0 + rh*64 + lane;
    const int b = m >> 12, h = (m >> 6) & 63, w = m & 63;
    cell[rh] = (b*66 + h)*66 + w;     // pad base (+1,+1 comes via ty/tx in 0..2)
  }

  for(int it=0; it<12; it++){
    const int k0 = (it0 + it)*64;
    const int tp = k0 >> 8;                 // 256 k per tap
    const int ty = tp/3, tx = tp - ty*3;
    const int kb8 = (k0 & 255) >> 3;        // chunk-of-8 base within tap
#pragma unroll
    for(int i=0;i<4;i++){
      const int tt = wid*4 + i, kc = tt >> 1, rh = tt & 1;
      cp16(a_in + ((size_t)(cell[rh] + ty*66 + tx))*256 + (kb8 + kc)*8, &A[kc][rh*64][0]);
    }
#pragma unroll
    for(int i=0;i<4;i++){
      const int tt = wid*4 + i, kc = tt >> 1, nh = tt & 1;
      cp16(wt + ((size_t)((k0>>3) + kc)*256 + n0 + nh*64 + lane)*8, &B[kc][nh*64][0]);
    }
    __syncthreads();
#pragma unroll
    for(int ks=0; ks<2; ks++){
      s16x8 af[4], bf[4];
#pragma unroll
      for(int mf=0;mf<4;mf++) af[mf] = Ap[(ks*4+quad)*128 + m_w + mf*16 + ln];
#pragma unroll
      for(int nf=0;nf<4;nf++) bf[nf] = Bp[(ks*4+quad)*128 + n_w + nf*16 + ln];
#pragma unroll
      for(int mf=0;mf<4;mf++)
#pragma unroll
        for(int nf=0;nf<4;nf++)
          acc[mf][nf] = mfma16(af[mf], bf[nf], acc[mf][nf]);
    }
    __syncthreads();
  }
#pragma unroll
  for(int mf=0;mf<4;mf++)
#pragma unroll
    for(int nf=0;nf<4;nf++){
      const int col = n0 + n_w + nf*16 + ln;
#pragma unroll
      for(int i=0;i<4;i++){
        const int row = m0 + m_w + mf*16 + quad*4 + i;
        unsafeAtomicAdd(outa + (size_t)row*256 + col, acc[mf][nf][i]);
      }
    }
}

// ---------------- BN stats: per-channel sum/sumsq over M=16384 ----------------
__global__ void k_stats(const float* __restrict__ acc, float* __restrict__ sum,
                        float* __restrict__ sq){
  const int m0 = blockIdx.x*64;
  const int c = threadIdx.x;
  float s = 0.f, q = 0.f;
  for(int i=0;i<64;i++){
    float v = acc[(size_t)(m0+i)*256 + c];
    s += v; q += v*v;
  }
  unsafeAtomicAdd(sum + c, s);
  unsafeAtomicAdd(sq + c, q);
}

// ---------------- BN1 + ReLU -> padded bf16 NHWC ----------------
__global__ void k_bn1(const float* __restrict__ acc, const float* __restrict__ sum,
                      const float* __restrict__ sq, const float* __restrict__ g,
                      const float* __restrict__ bt, u16* __restrict__ o){
  __shared__ float sc[256], sh[256];
  const int t = threadIdx.x;
  {
    float mean = sum[t] * (1.f/16384.f);
    float var  = sq[t] * (1.f/16384.f) - mean*mean;
    float rstd = rsqrtf(var + 1e-5f);
    float s = g[t] * rstd;
    sc[t] = s; sh[t] = bt[t] - mean*s;
  }
  __syncthreads();
  const int c4 = (t & 63) * 4;
  const float s0 = sc[c4], s1 = sc[c4+1], s2 = sc[c4+2], s3 = sc[c4+3];
  const float h0 = sh[c4], h1 = sh[c4+1], h2 = sh[c4+2], h3 = sh[c4+3];
#pragma unroll
  for(int k=0;k<4;k++){
    int m = blockIdx.x*16 + k*4 + (t>>6);
    int b = m >> 12, hh = (m >> 6) & 63, ww = m & 63;
    const float4 v = *(const float4*)(acc + (size_t)m*256 + c4);
    unsigned int lo = (unsigned int)(u16)f2bf(fmaxf(0.f, v.x*s0 + h0))
                    | ((unsigned int)(u16)f2bf(fmaxf(0.f, v.y*s1 + h1)) << 16);
    unsigned int hi = (unsigned int)(u16)f2bf(fmaxf(0.f, v.z*s2 + h2))
                    | ((unsigned int)(u16)f2bf(fmaxf(0.f, v.w*s3 + h3)) << 16);
    uint2 pr; pr.x = lo; pr.y = hi;
    *(uint2*)(o + ((size_t)(b*66 + hh+1)*66 + ww+1)*256 + c4) = pr;
  }
}

// ---------------- BN2 + ReLU + NHWC->NCHW fp32 output ----------------
__global__ void k_bn2_out(const float* __restrict__ acc, const float* __restrict__ sum,
                          const float* __restrict__ sq, const float* __restrict__ g,
                          const float* __restrict__ bt, float* __restrict__ out){
  __shared__ float tile[64][65];
  __shared__ float sc[64], sh[64];
  const int t = threadIdx.x;
  const int b = blockIdx.z, c0 = blockIdx.y*64, hw0 = blockIdx.x*64;
  if(t < 64){
    int c = c0 + t;
    float mean = sum[c] * (1.f/16384.f);
    float var  = sq[c] * (1.f/16384.f) - mean*mean;
    float rstd = rsqrtf(var + 1e-5f);
    float s = g[c] * rstd;
    sc[t] = s; sh[t] = bt[c] - mean*s;
  }
  __syncthreads();
#pragma unroll
  for(int k=0;k<16;k++){
    int idx = t + k*256;
    int wl = idx >> 6, cl = idx & 63;
    float v = acc[(size_t)((b<<12) + hw0 + wl)*256 + c0 + cl];
    tile[wl][cl] = fmaxf(0.f, v*sc[cl] + sh[cl]);
  }
  __syncthreads();
#pragma unroll
  for(int k=0;k<16;k++){
    int idx = t + k*256;
    int cl = idx >> 6, wl = idx & 63;
    out[(size_t)(b*256 + c0 + cl)*4096 + hw0 + wl] = tile[wl][cl];
  }
}

extern "C" void kernel_launch(void* const* d_in, const int* in_sizes, int n_in,
                              void* d_out, int out_size, void* d_ws, size_t ws_size,
                              hipStream_t stream){
  const float* in_v  = (const float*)d_in[0];
  const float* in_i  = (const float*)d_in[1];
  const float* w_off = (const float*)d_in[2];
  const float* b_off = (const float*)d_in[3];
  const float* w_dcn = (const float*)d_in[4];
  const float* g1    = (const float*)d_in[5];
  const float* bt1   = (const float*)d_in[6];
  const float* w2    = (const float*)d_in[7];
  const float* g2    = (const float*)d_in[8];
  const float* bt2   = (const float*)d_in[9];
  float* out = (float*)d_out;
  char* ws = (char*)d_ws;

  float* off_acc  = (float*)(ws + OFF_ACC_B);
  float* out1_acc = (float*)(ws + OUT1_ACC_B);
  float* out2_acc = (float*)(ws + OUT2_ACC_B);
  float* stats    = (float*)(ws + STATS_B);
  float* sum1 = stats,       *sq1 = stats + 256;
  float* sum2 = stats + 512, *sq2 = stats + 768;
  u16* xn_pad    = (u16*)(ws + XN_PAD_B);
  u16* out1n_pad = (u16*)(ws + OUT1N_PAD_B);
  u16* wofft = (u16*)(ws + WOFFT_B);
  u16* wdcnt = (u16*)(ws + WDCNT_B);
  u16* w2t   = (u16*)(ws + W2T_B);
  int*   samp_o = (int*)(ws + SAMP_O_B);
  float* samp_w = (float*)(ws + SAMP_W_B);
  u16* a_samp = (u16*)(ws + A_SAMP_B);

  hipMemsetAsync(ws, 0, ZERO_BYTES, stream);
  k_border<<<1040, 256, 0, stream>>>(xn_pad, out1n_pad);
  k_x_to_nhwc<<<dim3(64,8,4), 256, 0, stream>>>(in_v, in_i, xn_pad);
  k_prep_woff<<<576, 256, 0, stream>>>(w_off, wofft);
  k_prep_wdcn<<<4608, 256, 0, stream>>>(w_dcn, wdcnt);
  k_prep_w2<<<2304, 256, 0, stream>>>(w2, w2t);
  k_conv_off<<<dim3(256,6), 256, 0, stream>>>(xn_pad, wofft, off_acc);
  k_sampler<<<576, 256, 0, stream>>>(off_acc, b_off, samp_o, samp_w);
  k_sample_a<<<2304, 256, 0, stream>>>(xn_pad, samp_o, samp_w, a_samp);
  k_dcn_gemm<<<dim3(128,2,3), 256, 0, stream>>>(a_samp, wdcnt, out1_acc);
  k_stats<<<256, 256, 0, stream>>>(out1_acc, sum1, sq1);
  k_bn1<<<1024, 256, 0, stream>>>(out1_acc, sum1, sq1, g1, bt1, out1n_pad);
  k_conv2<<<dim3(128,2,3), 256, 0, stream>>>(out1n_pad, w2t, out2_acc);
  k_stats<<<256, 256, 0, stream>>>(out2_acc, sum2, sq2);
  k_bn2_out<<<dim3(64,4,4), 256, 0, stream>>>(out2_acc, sum2, sq2, g2, bt2, out);
}